// Round 3
// baseline (5855.057 us; speedup 1.0000x reference)
//
#include <hip/hip_runtime.h>
#include <hip/hip_bf16.h>

// All float tensors are fp32 (reference dtypes); values are bf16-quantized by the
// harness but STORED as float32. fps_idx is int32. Output is float32.

constexpr int BB = 16, NN = 4096, SS = 1024, DD = 64, KK = 32;
constexpr int PP = BB * SS * KK;            // 524288 grouped points
constexpr float EPSF = 1e-5f;

// Workspace layout (float offsets). Total ~1.29 MB.
constexpr int WS_IDX   = 0;                  // ushort[PP] neighbor indices (PP/2 floats)
constexpr int WS_NXYZ  = PP / 2;             // float[B*S*3] fp32 new_xyz
constexpr int WS_W0F   = WS_NXYZ + BB*SS*3;  // float[64*68] fp32 w0, k-padded to 68 with 0
constexpr int WS_W1P   = WS_W0F + 64*68;     // uint[2048] bf16-packed w1 (64x64)
constexpr int WS_W2P   = WS_W1P + 2048;      // uint[4096] bf16-packed w2 (128x64)
constexpr int WS_SUMS  = WS_W2P + 4096;      // float[512]: sum1 sq1 sum2 sq2 sum3[128] sq3[128]
constexpr int WS_SCALE = WS_SUMS + 512;      // float[512]: sc1 sh1 sc2 sh2 sc3[128] sh3[128]

__device__ __forceinline__ float blo(unsigned u) { return __uint_as_float(u << 16); }
__device__ __forceinline__ float bhi(unsigned u) { return __uint_as_float(u & 0xffff0000u); }
__device__ __forceinline__ unsigned rtne16(float x) {
    unsigned b = __float_as_uint(x);
    return (b + 0x7fffu + ((b >> 16) & 1u)) >> 16;   // round-to-nearest-even bf16 bits
}

// Same-wave LDS write->read ordering: drain DS queue + compiler memory barrier.
#define LDS_SYNC() asm volatile("s_waitcnt lgkmcnt(0)" ::: "memory")

// ---------------- prep: fp32 w0 (padded), bf16-pack w1/w2, zero stats ----------------
__global__ void k_prep(const float* __restrict__ w0, const float* __restrict__ w1,
                       const float* __restrict__ w2, float* __restrict__ ws) {
    const int t = threadIdx.x;
    float* w0f = ws + WS_W0F;
    for (int i = t; i < 64 * 68; i += 256) {
        int c = i / 68, k = i % 68;
        w0f[i] = (k < 67) ? w0[c * 67 + k] : 0.f;
    }
    unsigned* w1p = (unsigned*)(ws + WS_W1P);
    for (int i = t; i < 2048; i += 256) {           // w1: 64 rows x 32 pairs
        int o = i >> 5, p = i & 31;
        w1p[i] = rtne16(w1[o*64 + 2*p]) | (rtne16(w1[o*64 + 2*p + 1]) << 16);
    }
    unsigned* w2p = (unsigned*)(ws + WS_W2P);
    for (int i = t; i < 4096; i += 256) {           // w2: 128 rows x 32 pairs
        int o = i >> 5, p = i & 31;
        w2p[i] = rtne16(w2[o*64 + 2*p]) | (rtne16(w2[o*64 + 2*p + 1]) << 16);
    }
    for (int i = t; i < 512; i += 256) ws[WS_SUMS + i] = 0.f;
}

// ---------------- select: exact top-32 nearest neighbors per query ----------------
// One wave per query. 64 flipped-fp32 distance keys per lane in registers.
// Exact rank-32 threshold by binary search; stable (index-ascending) emission via
// ballot, matching jax.lax.top_k tie-breaking (lower index wins at equal distance).
__global__ __launch_bounds__(256, 2) void k_select(
    const float* __restrict__ xyz, const int* __restrict__ fps,
    float* __restrict__ out_xyz, float* __restrict__ ws)
{
    __shared__ float sx[NN], sy[NN], sz[NN];   // 48 KB fp32 coords for this batch
    const int tid = threadIdx.x;
    const int qb = blockIdx.x * 4;       // 4 queries per block (4 waves)
    const int b  = qb >> 10;             // S = 1024
    const float* xb = xyz + (long)b * NN * 3;
    for (int i = tid; i < NN; i += 256) {
        sx[i] = xb[i*3 + 0];
        sy[i] = xb[i*3 + 1];
        sz[i] = xb[i*3 + 2];
    }
    __syncthreads();

    const int wave = tid >> 6, lane = tid & 63;
    const int q = qb + wave;
    const int nq = fps[q];
    const float qx = sx[nq], qy = sy[nq], qz = sz[nq];
    const float qw = __fadd_rn(__fadd_rn(__fmul_rn(qx,qx), __fmul_rn(qy,qy)), __fmul_rn(qz,qz));

    float* nxyz = ws + WS_NXYZ;
    unsigned short* idx_ws = (unsigned short*)ws;
    if (lane < 3) {
        float v = (lane == 0) ? qx : ((lane == 1) ? qy : qz);
        out_xyz[q*3 + lane] = v;         // exact copy of the gathered coordinate
        nxyz[q*3 + lane] = v;
    }

    // keys: order-preserving flip of fp32 distance bits (asc key == asc distance)
    unsigned key[64];
    #pragma unroll
    for (int i = 0; i < 64; ++i) {
        const int n = i*64 + lane;
        const float px = sx[n], py = sy[n], pz = sz[n];
        const float pw = __fadd_rn(__fadd_rn(__fmul_rn(px,px), __fmul_rn(py,py)), __fmul_rn(pz,pz));
        float dot = fmaf(qx, px, 0.f);
        dot = fmaf(qy, py, dot);
        dot = fmaf(qz, pz, dot);
        float d = __fadd_rn(__fadd_rn(__fmul_rn(-2.0f, dot), qw), pw);
        unsigned u = __float_as_uint(d);
        key[i] = u ^ (unsigned)(((int)u >> 31) | 0x80000000);
    }

    // binary search smallest T with count(key <= T) >= 32 (wave-uniform)
    unsigned lo = 0u, hi = 0xFFFFFFFFu;
    while (lo < hi) {
        unsigned mid = lo + ((hi - lo) >> 1);
        int c = 0;
        #pragma unroll
        for (int i = 0; i < 64; ++i) c += (key[i] <= mid) ? 1 : 0;
        #pragma unroll
        for (int off = 32; off > 0; off >>= 1) c += __shfl_xor(c, off);
        if (c >= 32) hi = mid; else lo = mid + 1;
    }
    const unsigned T = lo;

    const unsigned long long lmask = (1ull << lane) - 1ull;
    int cnt = 0;
    const int base = q * KK;
    #pragma unroll
    for (int i = 0; i < 64; ++i) {       // all strictly-closer points (count < 32 guaranteed)
        bool pr = key[i] < T;
        unsigned long long m = __ballot(pr);
        if (pr) idx_ws[base + cnt + (int)__popcll(m & lmask)] = (unsigned short)(i*64 + lane);
        cnt += (int)__popcll(m);
    }
    #pragma unroll
    for (int i = 0; i < 64; ++i) {       // fill remaining slots with ties, smallest index first
        bool pr = key[i] == T;
        unsigned long long m = __ballot(pr);
        int pos = cnt + (int)__popcll(m & lmask);
        if (pr && pos < KK) idx_ws[base + pos] = (unsigned short)(i*64 + lane);
        cnt += (int)__popcll(m);
    }
}

// ---------------- MLP passes ----------------
// One point per wave; lane = output channel. x/h broadcast through a per-wave LDS
// region; weights in registers (w0 fp32, w1/w2 bf16-packed — lossless, values are
// bf16-grid). STAGE 1: L1 preact -> stats1;  STAGE 2: +BN1+L2 -> stats2;
// STAGE 3: +BN2+L3 -> stats3;  STAGE 4: +BN3+ReLU+max over K -> output.
template<int STAGE>
__global__ __launch_bounds__(256, 2) void k_pass(
    const float* __restrict__ xyz, const float* __restrict__ pts,
    const float* __restrict__ bb0, const float* __restrict__ bb1,
    const float* __restrict__ bb2,
    float* __restrict__ ws, float* __restrict__ out_pts)
{
    __shared__ float sh[4 * 196];   // per wave: x[0..67] h1[68..131] h2[132..195]
    const int tid = threadIdx.x;
    const int wave = tid >> 6, lane = tid & 63;
    float* xs = sh + wave * 196;

    const float* w0f  = ws + WS_W0F;
    const unsigned short* idxw = (const unsigned short*)ws;
    const float* nxyz = ws + WS_NXYZ;
    const float* scl  = ws + WS_SCALE;
    float*       sums = ws + WS_SUMS;

    // weights into registers
    float4 w0r[17];
    #pragma unroll
    for (int t = 0; t < 17; ++t) w0r[t] = ((const float4*)w0f)[lane*17 + t];
    float bias0 = bb0[lane];

    uint4 w1p[8]; float bias1 = 0.f, sc1 = 0.f, sf1 = 0.f;
    if constexpr (STAGE >= 2) {
        #pragma unroll
        for (int t = 0; t < 8; ++t) w1p[t] = ((const uint4*)(ws + WS_W1P))[lane*8 + t];
        bias1 = bb1[lane];
        sc1 = scl[lane]; sf1 = scl[64 + lane];
    }
    uint4 w2pa[8], w2pb[8]; float bias2a = 0.f, bias2b = 0.f, sc2 = 0.f, sf2 = 0.f;
    if constexpr (STAGE >= 3) {
        #pragma unroll
        for (int t = 0; t < 8; ++t) {
            w2pa[t] = ((const uint4*)(ws + WS_W2P))[lane*8 + t];
            w2pb[t] = ((const uint4*)(ws + WS_W2P))[(lane + 64)*8 + t];
        }
        bias2a = bb2[lane]; bias2b = bb2[lane + 64];
        sc2 = scl[128 + lane]; sf2 = scl[192 + lane];
    }
    float sc3a = 0.f, sf3a = 0.f, sc3b = 0.f, sf3b = 0.f;
    if constexpr (STAGE == 4) {
        sc3a = scl[256 + lane]; sc3b = scl[320 + lane];
        sf3a = scl[384 + lane]; sf3b = scl[448 + lane];
    }

    if (lane == 0) xs[67] = 0.f;   // pad slot (w0f[...][67] == 0 anyway)

    float s1 = 0.f, s2 = 0.f, s3 = 0.f, s4 = 0.f;   // stats accumulators
    float m0 = 0.f, m1 = 0.f;                        // stage-4 max (ReLU => >= 0)

    const int gw = blockIdx.x * 4 + wave;
    constexpr int NPT = (STAGE == 4) ? KK : 64;
    const int pbase = gw * NPT;

    // prefetch point 0
    int n = idxw[pbase];
    int q = pbase >> 5;
    long rowp = (long)(q >> 10) * NN + n;
    float pv = pts[rowp * DD + lane];
    float xv = 0.f, nxv = 0.f;
    if (lane < 3) { xv = xyz[rowp * 3 + lane]; nxv = nxyz[q*3 + lane]; }

    for (int it = 0; it < NPT; ++it) {
        // stage this point's 67 inputs into the per-wave LDS region
        xs[3 + lane] = pv;
        if (lane < 3) xs[lane] = __fadd_rn(xv, -nxv);
        LDS_SYNC();

        // prefetch next point (latency hidden under compute below)
        if (it + 1 < NPT) {
            int p2 = pbase + it + 1;
            int n2 = idxw[p2];
            int q2 = p2 >> 5;
            long rp2 = (long)(q2 >> 10) * NN + n2;
            pv = pts[rp2 * DD + lane];
            if (lane < 3) { xv = xyz[rp2 * 3 + lane]; nxv = nxyz[q2*3 + lane]; }
        }

        // L1: h1[lane] = b0 + sum_k w0[lane][k] * x[k]
        float a0 = bias0, a1 = 0.f, a2 = 0.f, a3 = 0.f;
        #pragma unroll
        for (int t = 0; t < 17; ++t) {
            float4 xq = ((const float4*)xs)[t];
            float4 wv = w0r[t];
            a0 = fmaf(wv.x, xq.x, a0); a1 = fmaf(wv.y, xq.y, a1);
            a2 = fmaf(wv.z, xq.z, a2); a3 = fmaf(wv.w, xq.w, a3);
        }
        float h1v = (a0 + a1) + (a2 + a3);
        if constexpr (STAGE == 1) { s1 += h1v; s2 += h1v * h1v; }

        if constexpr (STAGE >= 2) {
            float z1 = fmaxf(fmaf(h1v, sc1, sf1), 0.f);
            xs[68 + lane] = z1;
            LDS_SYNC();
            float c0 = bias1, c1 = 0.f, c2 = 0.f, c3 = 0.f;
            const float4* h1s = (const float4*)(xs + 68);
            #pragma unroll
            for (int t = 0; t < 8; ++t) {
                uint4 wp = w1p[t];
                float4 ha = h1s[2*t], hb = h1s[2*t + 1];
                c0 = fmaf(blo(wp.x), ha.x, c0); c1 = fmaf(bhi(wp.x), ha.y, c1);
                c2 = fmaf(blo(wp.y), ha.z, c2); c3 = fmaf(bhi(wp.y), ha.w, c3);
                c0 = fmaf(blo(wp.z), hb.x, c0); c1 = fmaf(bhi(wp.z), hb.y, c1);
                c2 = fmaf(blo(wp.w), hb.z, c2); c3 = fmaf(bhi(wp.w), hb.w, c3);
            }
            float h2v = (c0 + c1) + (c2 + c3);
            if constexpr (STAGE == 2) { s1 += h2v; s2 += h2v * h2v; }

            if constexpr (STAGE >= 3) {
                float z2 = fmaxf(fmaf(h2v, sc2, sf2), 0.f);
                xs[132 + lane] = z2;
                LDS_SYNC();
                float d0 = bias2a, d1 = 0.f, d2 = 0.f, d3 = 0.f;
                float e0 = bias2b, e1 = 0.f, e2 = 0.f, e3 = 0.f;
                const float4* h2s = (const float4*)(xs + 132);
                #pragma unroll
                for (int t = 0; t < 8; ++t) {
                    uint4 wa = w2pa[t], wb = w2pb[t];
                    float4 ha = h2s[2*t], hb = h2s[2*t + 1];
                    d0 = fmaf(blo(wa.x), ha.x, d0); d1 = fmaf(bhi(wa.x), ha.y, d1);
                    d2 = fmaf(blo(wa.y), ha.z, d2); d3 = fmaf(bhi(wa.y), ha.w, d3);
                    d0 = fmaf(blo(wa.z), hb.x, d0); d1 = fmaf(bhi(wa.z), hb.y, d1);
                    d2 = fmaf(blo(wa.w), hb.z, d2); d3 = fmaf(bhi(wa.w), hb.w, d3);
                    e0 = fmaf(blo(wb.x), ha.x, e0); e1 = fmaf(bhi(wb.x), ha.y, e1);
                    e2 = fmaf(blo(wb.y), ha.z, e2); e3 = fmaf(bhi(wb.y), ha.w, e3);
                    e0 = fmaf(blo(wb.z), hb.x, e0); e1 = fmaf(bhi(wb.z), hb.y, e1);
                    e2 = fmaf(blo(wb.w), hb.z, e2); e3 = fmaf(bhi(wb.w), hb.w, e3);
                }
                float h3a = (d0 + d1) + (d2 + d3);
                float h3b = (e0 + e1) + (e2 + e3);
                if constexpr (STAGE == 3) {
                    s1 += h3a; s2 += h3a * h3a;
                    s3 += h3b; s4 += h3b * h3b;
                }
                if constexpr (STAGE == 4) {
                    m0 = fmaxf(m0, fmaxf(fmaf(h3a, sc3a, sf3a), 0.f));
                    m1 = fmaxf(m1, fmaxf(fmaf(h3b, sc3b, sf3b), 0.f));
                }
            }
        }
    }

    if constexpr (STAGE == 1) {
        atomicAdd(&sums[lane], s1);       atomicAdd(&sums[64 + lane], s2);
    }
    if constexpr (STAGE == 2) {
        atomicAdd(&sums[128 + lane], s1); atomicAdd(&sums[192 + lane], s2);
    }
    if constexpr (STAGE == 3) {
        atomicAdd(&sums[256 + lane], s1); atomicAdd(&sums[384 + lane], s2);
        atomicAdd(&sums[320 + lane], s3); atomicAdd(&sums[448 + lane], s4);
    }
    if constexpr (STAGE == 4) {
        out_pts[(long)gw * 128 + lane]      = m0;
        out_pts[(long)gw * 128 + 64 + lane] = m1;
    }
}

// ---------------- finalize: mean/var -> BN scale/shift ----------------
__global__ void k_fin(const float* __restrict__ sums, const float* __restrict__ g,
                      const float* __restrict__ be, float* __restrict__ scl,
                      int sum_off, int sq_off, int sc_off, int sh_off, int C)
{
    int c = threadIdx.x;
    if (c < C) {
        float mean = sums[sum_off + c] * (1.0f / PP);
        float var  = sums[sq_off + c] * (1.0f / PP) - mean * mean;
        float s = g[c] * rsqrtf(var + EPSF);
        scl[sc_off + c] = s;
        scl[sh_off + c] = be[c] - mean * s;
    }
}

extern "C" void kernel_launch(void* const* d_in, const int* in_sizes, int n_in,
                              void* d_out, int out_size, void* d_ws, size_t ws_size,
                              hipStream_t stream) {
    const float* xyz = (const float*)d_in[0];
    const float* pts = (const float*)d_in[1];
    const int*   fps = (const int*)d_in[2];
    const float* w0  = (const float*)d_in[3];
    const float* b0  = (const float*)d_in[4];
    const float* g0  = (const float*)d_in[5];
    const float* be0 = (const float*)d_in[6];
    const float* w1  = (const float*)d_in[7];
    const float* b1  = (const float*)d_in[8];
    const float* g1  = (const float*)d_in[9];
    const float* be1 = (const float*)d_in[10];
    const float* w2  = (const float*)d_in[11];
    const float* b2  = (const float*)d_in[12];
    const float* g2  = (const float*)d_in[13];
    const float* be2 = (const float*)d_in[14];

    float* ws = (float*)d_ws;
    float* out_xyz = (float*)d_out;
    float* out_pts = (float*)d_out + BB * SS * 3;

    k_prep<<<1, 256, 0, stream>>>(w0, w1, w2, ws);
    k_select<<<BB * SS / 4, 256, 0, stream>>>(xyz, fps, out_xyz, ws);

    k_pass<1><<<PP / 256, 256, 0, stream>>>(xyz, pts, b0, b1, b2, ws, out_pts);
    k_fin<<<1, 128, 0, stream>>>(ws + WS_SUMS, g0, be0, ws + WS_SCALE, 0, 64, 0, 64, 64);

    k_pass<2><<<PP / 256, 256, 0, stream>>>(xyz, pts, b0, b1, b2, ws, out_pts);
    k_fin<<<1, 128, 0, stream>>>(ws + WS_SUMS, g1, be1, ws + WS_SCALE, 128, 192, 128, 192, 64);

    k_pass<3><<<PP / 256, 256, 0, stream>>>(xyz, pts, b0, b1, b2, ws, out_pts);
    k_fin<<<1, 128, 0, stream>>>(ws + WS_SUMS, g2, be2, ws + WS_SCALE, 256, 384, 256, 384, 128);

    k_pass<4><<<BB * SS / 4, 256, 0, stream>>>(xyz, pts, b0, b1, b2, ws, out_pts);
}

// Round 4
// 1059.331 us; speedup vs baseline: 5.5271x; 5.5271x over previous
//
#include <hip/hip_runtime.h>
#include <hip/hip_bf16.h>

// All float tensors are fp32 (reference dtypes, bf16-grid values). fps_idx int32.

typedef __attribute__((ext_vector_type(8))) short short8;
typedef __attribute__((ext_vector_type(4))) float float4v;

constexpr int BB = 16, NN = 4096, SS = 1024, DD = 64, KK = 32;
constexpr int PP = BB * SS * KK;            // 524288 grouped points
constexpr int NG = BB * SS;                 // 16384 query groups
constexpr float EPSF = 1e-5f;

// Workspace layout (float offsets). Total ~1.31 MB.
constexpr int WS_IDX   = 0;                  // ushort[PP] neighbor indices
constexpr int WS_NXYZ  = PP / 2;             // float[NG*3] fp32 new_xyz
constexpr int WS_W0PK  = WS_NXYZ + NG*3;     // ushort[6144]  frag-major W0' (K=96: 64 feat + xyz hi/lo + pad)
constexpr int WS_W1PK  = WS_W0PK + 3072;     // ushort[8192]  frag-major W1' (K=128, hi/lo dup)
constexpr int WS_W2PK  = WS_W1PK + 4096;     // ushort[16384] frag-major W2' (K=128, hi/lo dup)
constexpr int WS_SUMS  = WS_W2PK + 8192;     // float[512]
constexpr int WS_SCALE = WS_SUMS + 512;      // float[512]

__device__ __forceinline__ float blo(unsigned u) { return __uint_as_float(u << 16); }
__device__ __forceinline__ unsigned rtne16(float x) {
    unsigned b = __float_as_uint(x);
    return (b + 0x7fffu + ((b >> 16) & 1u)) >> 16;   // RTNE bf16 bits
}

union UF { uint4 u; short8 s; };
__device__ __forceinline__ short8 ldw(const uint4* __restrict__ p, int idx) {
    UF u; u.u = p[idx]; return u.s;
}
__device__ __forceinline__ short8 pack_bf8(float4 f0, float4 f1) {
    short8 r;
    r[0]=(short)rtne16(f0.x); r[1]=(short)rtne16(f0.y);
    r[2]=(short)rtne16(f0.z); r[3]=(short)rtne16(f0.w);
    r[4]=(short)rtne16(f1.x); r[5]=(short)rtne16(f1.y);
    r[6]=(short)rtne16(f1.z); r[7]=(short)rtne16(f1.w);
    return r;
}

// Same-wave LDS write->read ordering.
#define LDS_SYNC() asm volatile("s_waitcnt lgkmcnt(0)" ::: "memory")

// ---------------- prep: frag-major bf16 weight images + zero stats ----------------
__global__ void k_prep(const float* __restrict__ w0, const float* __restrict__ w1,
                       const float* __restrict__ w2, float* __restrict__ ws) {
    const int t = threadIdx.x;
    ushort* w0pk = (ushort*)(ws + WS_W0PK);
    for (int i = t; i < 6144; i += 256) {        // [Nt(4)][Ks(3)][lane(64)][j(8)]
        int j = i & 7, l = (i >> 3) & 63, Ks = (i >> 9) % 3, Nt = i / 1536;
        int o = Nt*16 + (l & 15);
        int k = Ks*32 + (l >> 4)*8 + j;
        float v = 0.f;
        if (k < 64)      v = w0[o*67 + 3 + k];        // point features
        else if (k < 67) v = w0[o*67 + (k - 64)];     // xyz (hi part)
        else if (k < 70) v = w0[o*67 + (k - 67)];     // xyz (lo part, same weights)
        w0pk[i] = (ushort)rtne16(v);
    }
    ushort* w1pk = (ushort*)(ws + WS_W1PK);
    for (int i = t; i < 8192; i += 256) {        // [Nt(4)][Ks(4)][lane][j]; k=2c hi, 2c+1 lo
        int j = i & 7, l = (i >> 3) & 63, Ks = (i >> 9) & 3, Nt = i >> 11;
        int o = Nt*16 + (l & 15);
        int c = (Ks*32 + (l >> 4)*8 + j) >> 1;
        w1pk[i] = (ushort)rtne16(w1[o*64 + c]);
    }
    ushort* w2pk = (ushort*)(ws + WS_W2PK);
    for (int i = t; i < 16384; i += 256) {       // [Nt(8)][Ks(4)][lane][j]
        int j = i & 7, l = (i >> 3) & 63, Ks = (i >> 9) & 3, Nt = i >> 11;
        int o = Nt*16 + (l & 15);
        int c = (Ks*32 + (l >> 4)*8 + j) >> 1;
        w2pk[i] = (ushort)rtne16(w2[o*64 + c]);
    }
    for (int i = t; i < 512; i += 256) ws[WS_SUMS + i] = 0.f;
}

// ---------------- select: exact top-32 nearest neighbors per query ----------------
__global__ __launch_bounds__(256, 2) void k_select(
    const float* __restrict__ xyz, const int* __restrict__ fps,
    float* __restrict__ out_xyz, float* __restrict__ ws)
{
    __shared__ float sx[NN], sy[NN], sz[NN];   // 48 KB fp32 coords for this batch
    const int tid = threadIdx.x;
    const int qb = blockIdx.x * 4;
    const int b  = qb >> 10;
    const float* xb = xyz + (long)b * NN * 3;
    for (int i = tid; i < NN; i += 256) {
        sx[i] = xb[i*3 + 0];
        sy[i] = xb[i*3 + 1];
        sz[i] = xb[i*3 + 2];
    }
    __syncthreads();

    const int wave = tid >> 6, lane = tid & 63;
    const int q = qb + wave;
    const int nq = fps[q];
    const float qx = sx[nq], qy = sy[nq], qz = sz[nq];
    const float qw = __fadd_rn(__fadd_rn(__fmul_rn(qx,qx), __fmul_rn(qy,qy)), __fmul_rn(qz,qz));

    float* nxyz = ws + WS_NXYZ;
    unsigned short* idx_ws = (unsigned short*)ws;
    if (lane < 3) {
        float v = (lane == 0) ? qx : ((lane == 1) ? qy : qz);
        out_xyz[q*3 + lane] = v;
        nxyz[q*3 + lane] = v;
    }

    unsigned key[64];
    #pragma unroll
    for (int i = 0; i < 64; ++i) {
        const int n = i*64 + lane;
        const float px = sx[n], py = sy[n], pz = sz[n];
        const float pw = __fadd_rn(__fadd_rn(__fmul_rn(px,px), __fmul_rn(py,py)), __fmul_rn(pz,pz));
        float dot = fmaf(qx, px, 0.f);
        dot = fmaf(qy, py, dot);
        dot = fmaf(qz, pz, dot);
        float d = __fadd_rn(__fadd_rn(__fmul_rn(-2.0f, dot), qw), pw);
        unsigned u = __float_as_uint(d);
        key[i] = u ^ (unsigned)(((int)u >> 31) | 0x80000000);
    }

    unsigned lo = 0u, hi = 0xFFFFFFFFu;
    while (lo < hi) {
        unsigned mid = lo + ((hi - lo) >> 1);
        int c = 0;
        #pragma unroll
        for (int i = 0; i < 64; ++i) c += (key[i] <= mid) ? 1 : 0;
        #pragma unroll
        for (int off = 32; off > 0; off >>= 1) c += __shfl_xor(c, off);
        if (c >= 32) hi = mid; else lo = mid + 1;
    }
    const unsigned T = lo;

    const unsigned long long lmask = (1ull << lane) - 1ull;
    int cnt = 0;
    const int base = q * KK;
    #pragma unroll
    for (int i = 0; i < 64; ++i) {
        bool pr = key[i] < T;
        unsigned long long m = __ballot(pr);
        if (pr) idx_ws[base + cnt + (int)__popcll(m & lmask)] = (unsigned short)(i*64 + lane);
        cnt += (int)__popcll(m);
    }
    #pragma unroll
    for (int i = 0; i < 64; ++i) {
        bool pr = key[i] == T;
        unsigned long long m = __ballot(pr);
        int pos = cnt + (int)__popcll(m & lmask);
        if (pr && pos < KK) idx_ws[base + pos] = (unsigned short)(i*64 + lane);
        cnt += (int)__popcll(m);
    }
}

// ---------------- MLP passes (MFMA) ----------------
// One wave per query group (32 points). GEMM1 K=96 (feat 64 exact-bf16 + xyz hi/lo),
// GEMM2/3 K=128 (activations split hi/lo, weights duplicated per parity).
// B-fragments streamed from frag-major global images (L2-resident).
// Z round-trips through a per-wave padded LDS buffer (C-layout -> A-layout).
template<int STAGE>
__global__ __launch_bounds__(256, 2) void k_pass(
    const float* __restrict__ xyz, const float* __restrict__ pts,
    const float* __restrict__ b0, const float* __restrict__ b1,
    const float* __restrict__ b2,
    float* __restrict__ ws, float* __restrict__ out_pts)
{
    __shared__ __align__(16) ushort zb[4][32][136];   // per-wave Z buffer, +8 pad
    const int tid = threadIdx.x;
    const int wv = tid >> 6, l = tid & 63, ln = l & 15, q8 = l >> 4;

    const ushort* idxw = (const ushort*)ws;
    const float* nxyz = ws + WS_NXYZ;
    const float* scl  = ws + WS_SCALE;
    float*       sums = ws + WS_SUMS;
    const uint4* w0f = (const uint4*)(ws + WS_W0PK);
    const uint4* w1f = (const uint4*)(ws + WS_W1PK);
    const uint4* w2f = (const uint4*)(ws + WS_W2PK);

    float b0v[4];
    #pragma unroll
    for (int n = 0; n < 4; ++n) b0v[n] = b0[n*16 + ln];
    float sc1v[4], sf1v[4], b1v[4];
    if constexpr (STAGE >= 2) {
        #pragma unroll
        for (int n = 0; n < 4; ++n) {
            sc1v[n] = scl[n*16 + ln]; sf1v[n] = scl[64 + n*16 + ln];
            b1v[n] = b1[n*16 + ln];
        }
    }
    float sc2v[4], sf2v[4], b2v[8];
    if constexpr (STAGE >= 3) {
        #pragma unroll
        for (int n = 0; n < 4; ++n) {
            sc2v[n] = scl[128 + n*16 + ln]; sf2v[n] = scl[192 + n*16 + ln];
        }
        #pragma unroll
        for (int n = 0; n < 8; ++n) b2v[n] = b2[n*16 + ln];
    }
    float sc3v[8], sf3v[8];
    if constexpr (STAGE == 4) {
        #pragma unroll
        for (int n = 0; n < 8; ++n) {
            sc3v[n] = scl[256 + n*16 + ln]; sf3v[n] = scl[384 + n*16 + ln];
        }
    }

    float s[8] = {0,0,0,0,0,0,0,0}, sq[8] = {0,0,0,0,0,0,0,0};

    for (int g = blockIdx.x*4 + wv; g < NG; g += 4096) {
        // neighbor rows for this lane's two points (m = Mt*16 + ln)
        int rows[2];
        #pragma unroll
        for (int Mt = 0; Mt < 2; ++Mt) {
            int nb = idxw[g*32 + Mt*16 + ln];
            rows[Mt] = (g >> 10)*NN + nb;
        }
        const float nqx = nxyz[g*3+0], nqy = nxyz[g*3+1], nqz = nxyz[g*3+2];

        // A1 fragments: features (exact bf16) + xyz hi/lo in K-step 2
        short8 a1[2][3];
        #pragma unroll
        for (int Mt = 0; Mt < 2; ++Mt) {
            #pragma unroll
            for (int Ks = 0; Ks < 2; ++Ks) {
                const float* p = pts + rows[Mt]*64 + Ks*32 + q8*8;
                float4 f0 = *(const float4*)p;
                float4 f1 = *(const float4*)(p + 4);
                a1[Mt][Ks] = pack_bf8(f0, f1);
            }
            short8 x8 = {0,0,0,0,0,0,0,0};
            if (q8 == 0) {
                float vx = __fadd_rn(xyz[rows[Mt]*3+0], -nqx);
                float vy = __fadd_rn(xyz[rows[Mt]*3+1], -nqy);
                float vz = __fadd_rn(xyz[rows[Mt]*3+2], -nqz);
                unsigned hx = rtne16(vx), hy = rtne16(vy), hz = rtne16(vz);
                x8[0] = (short)hx; x8[1] = (short)hy; x8[2] = (short)hz;
                x8[3] = (short)rtne16(vx - blo(hx));
                x8[4] = (short)rtne16(vy - blo(hy));
                x8[5] = (short)rtne16(vz - blo(hz));
            }
            a1[Mt][2] = x8;
        }

        // GEMM1: H1 = X . W0'  (32 x 64)
        float4v acc1[2][4];
        #pragma unroll
        for (int Mt = 0; Mt < 2; ++Mt)
            #pragma unroll
            for (int Nt = 0; Nt < 4; ++Nt)
                acc1[Mt][Nt] = (float4v){b0v[Nt], b0v[Nt], b0v[Nt], b0v[Nt]};
        #pragma unroll
        for (int Ks = 0; Ks < 3; ++Ks)
            #pragma unroll
            for (int Nt = 0; Nt < 4; ++Nt) {
                short8 bf = ldw(w0f, (Nt*3 + Ks)*64 + l);
                #pragma unroll
                for (int Mt = 0; Mt < 2; ++Mt)
                    acc1[Mt][Nt] = __builtin_amdgcn_mfma_f32_16x16x32_bf16(
                        a1[Mt][Ks], bf, acc1[Mt][Nt], 0, 0, 0);
            }

        if constexpr (STAGE == 1) {
            #pragma unroll
            for (int Nt = 0; Nt < 4; ++Nt)
                #pragma unroll
                for (int Mt = 0; Mt < 2; ++Mt)
                    #pragma unroll
                    for (int r = 0; r < 4; ++r) {
                        float h = acc1[Mt][Nt][r];
                        s[Nt] += h; sq[Nt] += h*h;
                    }
            continue;
        }

        if constexpr (STAGE >= 2) {
            // Z1 = relu(bn1(H1)) -> hi/lo interleaved into zb
            #pragma unroll
            for (int Mt = 0; Mt < 2; ++Mt)
                #pragma unroll
                for (int Nt = 0; Nt < 4; ++Nt)
                    #pragma unroll
                    for (int r = 0; r < 4; ++r) {
                        float z = fmaxf(fmaf(acc1[Mt][Nt][r], sc1v[Nt], sf1v[Nt]), 0.f);
                        unsigned hb = rtne16(z);
                        unsigned lb = rtne16(z - blo(hb));
                        *(unsigned*)&zb[wv][Mt*16 + q8*4 + r][2*(Nt*16 + ln)] = hb | (lb << 16);
                    }
            LDS_SYNC();

            // GEMM2: H2 = Z1 . W1'  (32 x 64), K=128
            float4v acc2[2][4];
            #pragma unroll
            for (int Mt = 0; Mt < 2; ++Mt)
                #pragma unroll
                for (int Nt = 0; Nt < 4; ++Nt)
                    acc2[Mt][Nt] = (float4v){b1v[Nt], b1v[Nt], b1v[Nt], b1v[Nt]};
            #pragma unroll
            for (int Ks = 0; Ks < 4; ++Ks) {
                short8 a2[2];
                #pragma unroll
                for (int Mt = 0; Mt < 2; ++Mt)
                    a2[Mt] = *(const short8*)&zb[wv][Mt*16 + ln][Ks*32 + q8*8];
                #pragma unroll
                for (int Nt = 0; Nt < 4; ++Nt) {
                    short8 bf = ldw(w1f, (Nt*4 + Ks)*64 + l);
                    #pragma unroll
                    for (int Mt = 0; Mt < 2; ++Mt)
                        acc2[Mt][Nt] = __builtin_amdgcn_mfma_f32_16x16x32_bf16(
                            a2[Mt], bf, acc2[Mt][Nt], 0, 0, 0);
                }
            }

            if constexpr (STAGE == 2) {
                #pragma unroll
                for (int Nt = 0; Nt < 4; ++Nt)
                    #pragma unroll
                    for (int Mt = 0; Mt < 2; ++Mt)
                        #pragma unroll
                        for (int r = 0; r < 4; ++r) {
                            float h = acc2[Mt][Nt][r];
                            s[Nt] += h; sq[Nt] += h*h;
                        }
            }

            if constexpr (STAGE >= 3) {
                LDS_SYNC();   // all Z1 reads consumed; safe to overwrite
                #pragma unroll
                for (int Mt = 0; Mt < 2; ++Mt)
                    #pragma unroll
                    for (int Nt = 0; Nt < 4; ++Nt)
                        #pragma unroll
                        for (int r = 0; r < 4; ++r) {
                            float z = fmaxf(fmaf(acc2[Mt][Nt][r], sc2v[Nt], sf2v[Nt]), 0.f);
                            unsigned hb = rtne16(z);
                            unsigned lb = rtne16(z - blo(hb));
                            *(unsigned*)&zb[wv][Mt*16 + q8*4 + r][2*(Nt*16 + ln)] = hb | (lb << 16);
                        }
                LDS_SYNC();

                // GEMM3: H3 = Z2 . W2'  (32 x 128), K=128
                float4v acc3[2][8];
                #pragma unroll
                for (int Mt = 0; Mt < 2; ++Mt)
                    #pragma unroll
                    for (int Nt = 0; Nt < 8; ++Nt)
                        acc3[Mt][Nt] = (float4v){b2v[Nt], b2v[Nt], b2v[Nt], b2v[Nt]};
                #pragma unroll
                for (int Ks = 0; Ks < 4; ++Ks) {
                    short8 a2[2];
                    #pragma unroll
                    for (int Mt = 0; Mt < 2; ++Mt)
                        a2[Mt] = *(const short8*)&zb[wv][Mt*16 + ln][Ks*32 + q8*8];
                    #pragma unroll
                    for (int Nt = 0; Nt < 8; ++Nt) {
                        short8 bf = ldw(w2f, (Nt*4 + Ks)*64 + l);
                        #pragma unroll
                        for (int Mt = 0; Mt < 2; ++Mt)
                            acc3[Mt][Nt] = __builtin_amdgcn_mfma_f32_16x16x32_bf16(
                                a2[Mt], bf, acc3[Mt][Nt], 0, 0, 0);
                    }
                }

                if constexpr (STAGE == 3) {
                    #pragma unroll
                    for (int Nt = 0; Nt < 8; ++Nt)
                        #pragma unroll
                        for (int Mt = 0; Mt < 2; ++Mt)
                            #pragma unroll
                            for (int r = 0; r < 4; ++r) {
                                float h = acc3[Mt][Nt][r];
                                s[Nt] += h; sq[Nt] += h*h;
                            }
                }
                if constexpr (STAGE == 4) {
                    float mx[8];
                    #pragma unroll
                    for (int Nt = 0; Nt < 8; ++Nt) {
                        float m = 0.f;
                        #pragma unroll
                        for (int Mt = 0; Mt < 2; ++Mt)
                            #pragma unroll
                            for (int r = 0; r < 4; ++r)
                                m = fmaxf(m, fmaf(acc3[Mt][Nt][r], sc3v[Nt], sf3v[Nt]));
                        m = fmaxf(m, 0.f);   // relu
                        mx[Nt] = m;
                    }
                    #pragma unroll
                    for (int Nt = 0; Nt < 8; ++Nt) {
                        mx[Nt] = fmaxf(mx[Nt], __shfl_xor(mx[Nt], 16));
                        mx[Nt] = fmaxf(mx[Nt], __shfl_xor(mx[Nt], 32));
                    }
                    if (l < 16) {
                        #pragma unroll
                        for (int Nt = 0; Nt < 8; ++Nt)
                            out_pts[g*128 + Nt*16 + l] = mx[Nt];
                    }
                }
            }
        }
    }

    // stats: quad-reduce then one atomic burst per wave
    if constexpr (STAGE <= 3) {
        constexpr int NT = (STAGE == 3) ? 8 : 4;
        constexpr int soff = (STAGE == 1) ? 0 : (STAGE == 2) ? 128 : 256;
        constexpr int qoff = (STAGE == 1) ? 64 : (STAGE == 2) ? 192 : 384;
        #pragma unroll
        for (int t = 0; t < NT; ++t) {
            float a = s[t], b = sq[t];
            a += __shfl_xor(a, 16); a += __shfl_xor(a, 32);
            b += __shfl_xor(b, 16); b += __shfl_xor(b, 32);
            if (l < 16) {
                atomicAdd(&sums[soff + t*16 + l], a);
                atomicAdd(&sums[qoff + t*16 + l], b);
            }
        }
    }
}

// ---------------- finalize: mean/var -> BN scale/shift ----------------
__global__ void k_fin(const float* __restrict__ sums, const float* __restrict__ g,
                      const float* __restrict__ be, float* __restrict__ scl,
                      int sum_off, int sq_off, int sc_off, int sh_off, int C)
{
    int c = threadIdx.x;
    if (c < C) {
        float mean = sums[sum_off + c] * (1.0f / PP);
        float var  = sums[sq_off + c] * (1.0f / PP) - mean * mean;
        float s = g[c] * rsqrtf(var + EPSF);
        scl[sc_off + c] = s;
        scl[sh_off + c] = be[c] - mean * s;
    }
}

extern "C" void kernel_launch(void* const* d_in, const int* in_sizes, int n_in,
                              void* d_out, int out_size, void* d_ws, size_t ws_size,
                              hipStream_t stream) {
    const float* xyz = (const float*)d_in[0];
    const float* pts = (const float*)d_in[1];
    const int*   fps = (const int*)d_in[2];
    const float* w0  = (const float*)d_in[3];
    const float* b0  = (const float*)d_in[4];
    const float* g0  = (const float*)d_in[5];
    const float* be0 = (const float*)d_in[6];
    const float* w1  = (const float*)d_in[7];
    const float* b1  = (const float*)d_in[8];
    const float* g1  = (const float*)d_in[9];
    const float* be1 = (const float*)d_in[10];
    const float* w2  = (const float*)d_in[11];
    const float* b2  = (const float*)d_in[12];
    const float* g2  = (const float*)d_in[13];
    const float* be2 = (const float*)d_in[14];

    float* ws = (float*)d_ws;
    float* out_xyz = (float*)d_out;
    float* out_pts = (float*)d_out + NG * 3;

    k_prep<<<1, 256, 0, stream>>>(w0, w1, w2, ws);
    k_select<<<NG / 4, 256, 0, stream>>>(xyz, fps, out_xyz, ws);

    k_pass<1><<<1024, 256, 0, stream>>>(xyz, pts, b0, b1, b2, ws, out_pts);
    k_fin<<<1, 128, 0, stream>>>(ws + WS_SUMS, g0, be0, ws + WS_SCALE, 0, 64, 0, 64, 64);

    k_pass<2><<<1024, 256, 0, stream>>>(xyz, pts, b0, b1, b2, ws, out_pts);
    k_fin<<<1, 128, 0, stream>>>(ws + WS_SUMS, g1, be1, ws + WS_SCALE, 128, 192, 128, 192, 64);

    k_pass<3><<<1024, 256, 0, stream>>>(xyz, pts, b0, b1, b2, ws, out_pts);
    k_fin<<<1, 128, 0, stream>>>(ws + WS_SUMS, g2, be2, ws + WS_SCALE, 256, 384, 256, 384, 128);

    k_pass<4><<<1024, 256, 0, stream>>>(xyz, pts, b0, b1, b2, ws, out_pts);
}

// Round 5
// 1014.314 us; speedup vs baseline: 5.7724x; 1.0444x over previous
//
#include <hip/hip_runtime.h>
#include <hip/hip_bf16.h>

// All float tensors are fp32 (reference dtypes, bf16-grid values). fps_idx int32.

typedef __attribute__((ext_vector_type(8))) short short8;
typedef __attribute__((ext_vector_type(4))) float float4v;

constexpr int BB = 16, NN = 4096, SS = 1024, DD = 64, KK = 32;
constexpr int PP = BB * SS * KK;            // 524288 grouped points
constexpr int NG = BB * SS;                 // 16384 query groups
constexpr float EPSF = 1e-5f;

// Workspace layout (float offsets). Total ~1.31 MB.
constexpr int WS_IDX   = 0;                  // ushort[PP] neighbor indices
constexpr int WS_NXYZ  = PP / 2;             // float[NG*3] fp32 new_xyz
constexpr int WS_W0PK  = WS_NXYZ + NG*3;     // ushort[6144]  frag-major W0' (K=96)
constexpr int WS_W1PK  = WS_W0PK + 3072;     // ushort[8192]  frag-major W1' (K=128 hi/lo)
constexpr int WS_W2PK  = WS_W1PK + 4096;     // ushort[16384] frag-major W2' (K=128 hi/lo)
constexpr int WS_SUMS  = WS_W2PK + 8192;     // float[512]
constexpr int WS_SCALE = WS_SUMS + 512;      // float[512]

__device__ __forceinline__ unsigned rtne16(float x) {
    unsigned b = __float_as_uint(x);
    return (b + 0x7fffu + ((b >> 16) & 1u)) >> 16;
}
// bf16 RTNE bits left in [31:16]
__device__ __forceinline__ unsigned rtneb(float r) {
    unsigned b = __float_as_uint(r);
    return b + 0x7fffu + ((b >> 16) & 1u);
}
// pack: low16 = a[31:16], high16 = b[31:16]
__device__ __forceinline__ unsigned pk2r(unsigned a, unsigned b) {
    return __builtin_amdgcn_perm(a, b, 0x03020706u);
}
__device__ __forceinline__ unsigned pk2f(float a, float b) {
    return pk2r(__float_as_uint(a), __float_as_uint(b));
}

union UF { uint4 u; short8 s; };
__device__ __forceinline__ short8 ldw(const uint4* __restrict__ p, int idx) {
    UF u; u.u = p[idx]; return u.s;
}

#define LDS_SYNC() asm volatile("s_waitcnt lgkmcnt(0)" ::: "memory")

// ---------------- prep: frag-major bf16 weight images + zero stats ----------------
__global__ void k_prep(const float* __restrict__ w0, const float* __restrict__ w1,
                       const float* __restrict__ w2, float* __restrict__ ws) {
    const int t = threadIdx.x;
    ushort* w0pk = (ushort*)(ws + WS_W0PK);
    for (int i = t; i < 6144; i += 256) {        // [Nt(4)][Ks(3)][lane(64)][j(8)]
        int j = i & 7, l = (i >> 3) & 63, Ks = (i >> 9) % 3, Nt = i / 1536;
        int o = Nt*16 + (l & 15);
        int k = Ks*32 + (l >> 4)*8 + j;
        float v = 0.f;
        if (k < 64)      v = w0[o*67 + 3 + k];
        else if (k < 67) v = w0[o*67 + (k - 64)];     // xyz hi
        else if (k < 70) v = w0[o*67 + (k - 67)];     // xyz lo (same weights)
        w0pk[i] = (ushort)rtne16(v);
    }
    ushort* w1pk = (ushort*)(ws + WS_W1PK);
    for (int i = t; i < 8192; i += 256) {        // [Nt(4)][Ks(4)][lane][j]
        int j = i & 7, l = (i >> 3) & 63, Ks = (i >> 9) & 3, Nt = i >> 11;
        int o = Nt*16 + (l & 15);
        int c = (Ks*32 + (l >> 4)*8 + j) >> 1;
        w1pk[i] = (ushort)rtne16(w1[o*64 + c]);
    }
    ushort* w2pk = (ushort*)(ws + WS_W2PK);
    for (int i = t; i < 16384; i += 256) {       // [Nt(8)][Ks(4)][lane][j]
        int j = i & 7, l = (i >> 3) & 63, Ks = (i >> 9) & 3, Nt = i >> 11;
        int o = Nt*16 + (l & 15);
        int c = (Ks*32 + (l >> 4)*8 + j) >> 1;
        w2pk[i] = (ushort)rtne16(w2[o*64 + c]);
    }
    for (int i = t; i < 512; i += 256) ws[WS_SUMS + i] = 0.f;
}

// ---------------- select: exact top-32 nearest neighbors per query ----------------
// One wave per query. Count via ballot+scalar-popcount (no shuffle reductions);
// binary search narrowed to wave [min,max] key range; ballot-stable emission.
__global__ __launch_bounds__(256, 2) void k_select(
    const float* __restrict__ xyz, const int* __restrict__ fps,
    float* __restrict__ out_xyz, float* __restrict__ ws)
{
    __shared__ float sx[NN], sy[NN], sz[NN];
    const int tid = threadIdx.x;
    const int qb = blockIdx.x * 4;
    const int b  = qb >> 10;
    const float* xb = xyz + (long)b * NN * 3;
    for (int i = tid; i < NN; i += 256) {
        sx[i] = xb[i*3 + 0];
        sy[i] = xb[i*3 + 1];
        sz[i] = xb[i*3 + 2];
    }
    __syncthreads();

    const int wave = tid >> 6, lane = tid & 63;
    const int q = qb + wave;
    const int nq = fps[q];
    const float qx = sx[nq], qy = sy[nq], qz = sz[nq];
    const float qw = __fadd_rn(__fadd_rn(__fmul_rn(qx,qx), __fmul_rn(qy,qy)), __fmul_rn(qz,qz));

    float* nxyz = ws + WS_NXYZ;
    unsigned short* idx_ws = (unsigned short*)ws;
    if (lane < 3) {
        float v = (lane == 0) ? qx : ((lane == 1) ? qy : qz);
        out_xyz[q*3 + lane] = v;
        nxyz[q*3 + lane] = v;
    }

    unsigned key[64];
    unsigned kmin = 0xFFFFFFFFu, kmax = 0u;
    #pragma unroll
    for (int i = 0; i < 64; ++i) {
        const int n = i*64 + lane;
        const float px = sx[n], py = sy[n], pz = sz[n];
        const float pw = __fadd_rn(__fadd_rn(__fmul_rn(px,px), __fmul_rn(py,py)), __fmul_rn(pz,pz));
        float dot = fmaf(qx, px, 0.f);
        dot = fmaf(qy, py, dot);
        dot = fmaf(qz, pz, dot);
        float d = __fadd_rn(__fadd_rn(__fmul_rn(-2.0f, dot), qw), pw);
        unsigned u = __float_as_uint(d);
        unsigned k = u ^ (unsigned)(((int)u >> 31) | 0x80000000);
        key[i] = k;
        kmin = min(kmin, k); kmax = max(kmax, k);
    }
    #pragma unroll
    for (int off = 32; off > 0; off >>= 1) {
        kmin = min(kmin, (unsigned)__shfl_xor((int)kmin, off));
        kmax = max(kmax, (unsigned)__shfl_xor((int)kmax, off));
    }

    // smallest T in [kmin,kmax] with count(key <= T) >= 32; count on scalar pipe
    unsigned lo = kmin, hi = kmax;
    while (lo < hi) {
        unsigned mid = lo + ((hi - lo) >> 1);
        int c = 0;
        #pragma unroll
        for (int i = 0; i < 64; ++i)
            c += (int)__popcll(__ballot(key[i] <= mid));
        if (c >= 32) hi = mid; else lo = mid + 1;
    }
    const unsigned T = lo;

    const unsigned long long lmask = (1ull << lane) - 1ull;
    int cnt = 0;
    const int base = q * KK;
    #pragma unroll
    for (int i = 0; i < 64; ++i) {       // strictly-closer (count < 32 guaranteed)
        bool pr = key[i] < T;
        unsigned long long m = __ballot(pr);
        if (pr) idx_ws[base + cnt + (int)__popcll(m & lmask)] = (unsigned short)(i*64 + lane);
        cnt += (int)__popcll(m);
    }
    for (int i = 0; i < 64 && cnt < KK; ++i) {   // ties, smallest index first
        bool pr = key[i] == T;
        unsigned long long m = __ballot(pr);
        int pos = cnt + (int)__popcll(m & lmask);
        if (pr && pos < KK) idx_ws[base + pos] = (unsigned short)(i*64 + lane);
        cnt += (int)__popcll(m);
    }
}

// ---------------- MLP passes (MFMA) ----------------
// One wave per query group (32 points), 4 groups per wave. Prefetched gathers,
// G1 weights in registers, G2/G3 streamed (L1/L2-resident). STAGE 1: stats1;
// STAGE 2: +BN1+G2 stats2; STAGE 3: +BN2+G3 stats3 + pre-BN max/min pool -> out.
template<int STAGE>
__global__ __launch_bounds__(256, 2) void k_pass(
    const float* __restrict__ xyz, const float* __restrict__ pts,
    const float* __restrict__ b0, const float* __restrict__ b1,
    const float* __restrict__ b2, const float* __restrict__ g2,
    float* __restrict__ ws, float* __restrict__ out_pts)
{
    __shared__ __align__(16) ushort zb[(STAGE >= 2) ? 4*32*136 : 8];
    const int tid = threadIdx.x;
    const int wv = tid >> 6, l = tid & 63, ln = l & 15, q8 = l >> 4;
    ushort* zw = &zb[(STAGE >= 2) ? wv*32*136 : 0];

    const ushort* idxw = (const ushort*)ws;
    const float* nxyz = ws + WS_NXYZ;
    const float* scl  = ws + WS_SCALE;
    float*       sums = ws + WS_SUMS;
    const uint4* w0f = (const uint4*)(ws + WS_W0PK);
    const uint4* w1f = (const uint4*)(ws + WS_W1PK);
    const uint4* w2f = (const uint4*)(ws + WS_W2PK);

    // G1 weight fragments in registers for the whole kernel
    short8 w0r[12];
    #pragma unroll
    for (int t = 0; t < 12; ++t) w0r[t] = ldw(w0f, t*64 + l);

    float b0v[4];
    #pragma unroll
    for (int n = 0; n < 4; ++n) b0v[n] = b0[n*16 + ln];
    float sc1v[4], sf1v[4], b1v[4];
    if constexpr (STAGE >= 2) {
        #pragma unroll
        for (int n = 0; n < 4; ++n) {
            sc1v[n] = scl[n*16 + ln]; sf1v[n] = scl[64 + n*16 + ln];
            b1v[n] = b1[n*16 + ln];
        }
    }
    float sc2v[4], sf2v[4], b2v[8], g2v[8];
    if constexpr (STAGE >= 3) {
        #pragma unroll
        for (int n = 0; n < 4; ++n) {
            sc2v[n] = scl[128 + n*16 + ln]; sf2v[n] = scl[192 + n*16 + ln];
        }
        #pragma unroll
        for (int n = 0; n < 8; ++n) { b2v[n] = b2[n*16 + ln]; g2v[n] = g2[n*16 + ln]; }
    }

    float s[8] = {0,0,0,0,0,0,0,0}, sq[8] = {0,0,0,0,0,0,0,0};

    // double-buffered raw gathers
    float4 pf[2][2][4];
    float  xv[2][2][3];

    auto loadg = [&](int gv, float4 pfb[2][4], float xvb[2][3]) {
        #pragma unroll
        for (int Mt = 0; Mt < 2; ++Mt) {
            int nb = idxw[gv*32 + Mt*16 + ln];
            long row = (long)(gv >> 10)*NN + nb;
            const float* p = pts + row*64 + q8*8;
            pfb[Mt][0] = *(const float4*)p;
            pfb[Mt][1] = *(const float4*)(p + 4);
            pfb[Mt][2] = *(const float4*)(p + 32);
            pfb[Mt][3] = *(const float4*)(p + 36);
            if (q8 == 0) {
                xvb[Mt][0] = xyz[row*3 + 0];
                xvb[Mt][1] = xyz[row*3 + 1];
                xvb[Mt][2] = xyz[row*3 + 2];
            }
        }
    };

    const int gbase = blockIdx.x*4 + wv;
    loadg(gbase, pf[0], xv[0]);

    #pragma unroll
    for (int it = 0; it < 4; ++it) {
        const int g = gbase + it*4096;
        if (it < 3) loadg(g + 4096, pf[(it+1)&1], xv[(it+1)&1]);

        // pack A1 fragments
        short8 a1[2][3];
        {
            const float nqx = nxyz[g*3+0], nqy = nxyz[g*3+1], nqz = nxyz[g*3+2];
            const float4 (&pc)[2][4] = pf[it&1];
            const float (&xc)[2][3] = xv[it&1];
            #pragma unroll
            for (int Mt = 0; Mt < 2; ++Mt) {
                UF t0, t1;
                t0.u.x = pk2f(pc[Mt][0].x, pc[Mt][0].y);
                t0.u.y = pk2f(pc[Mt][0].z, pc[Mt][0].w);
                t0.u.z = pk2f(pc[Mt][1].x, pc[Mt][1].y);
                t0.u.w = pk2f(pc[Mt][1].z, pc[Mt][1].w);
                a1[Mt][0] = t0.s;
                t1.u.x = pk2f(pc[Mt][2].x, pc[Mt][2].y);
                t1.u.y = pk2f(pc[Mt][2].z, pc[Mt][2].w);
                t1.u.z = pk2f(pc[Mt][3].x, pc[Mt][3].y);
                t1.u.w = pk2f(pc[Mt][3].z, pc[Mt][3].w);
                a1[Mt][1] = t1.s;
                UF x; x.u = make_uint4(0,0,0,0);
                if (q8 == 0) {
                    float vx = xc[Mt][0] - nqx, vy = xc[Mt][1] - nqy, vz = xc[Mt][2] - nqz;
                    unsigned bx = __float_as_uint(vx), by = __float_as_uint(vy), bz = __float_as_uint(vz);
                    float rx = vx - __uint_as_float(bx & 0xffff0000u);
                    float ry = vy - __uint_as_float(by & 0xffff0000u);
                    float rz = vz - __uint_as_float(bz & 0xffff0000u);
                    x.u.x = pk2r(bx, by);
                    x.u.y = pk2r(bz, rtneb(rx));
                    x.u.z = pk2r(rtneb(ry), rtneb(rz));
                }
                a1[Mt][2] = x.s;
            }
        }

        // GEMM1: 32x64, K=96
        float4v acc1[2][4];
        #pragma unroll
        for (int Mt = 0; Mt < 2; ++Mt)
            #pragma unroll
            for (int Nt = 0; Nt < 4; ++Nt)
                acc1[Mt][Nt] = (float4v){b0v[Nt], b0v[Nt], b0v[Nt], b0v[Nt]};
        #pragma unroll
        for (int Ks = 0; Ks < 3; ++Ks)
            #pragma unroll
            for (int Nt = 0; Nt < 4; ++Nt)
                #pragma unroll
                for (int Mt = 0; Mt < 2; ++Mt)
                    acc1[Mt][Nt] = __builtin_amdgcn_mfma_f32_16x16x32_bf16(
                        a1[Mt][Ks], w0r[Nt*3 + Ks], acc1[Mt][Nt], 0, 0, 0);

        if constexpr (STAGE == 1) {
            #pragma unroll
            for (int Nt = 0; Nt < 4; ++Nt)
                #pragma unroll
                for (int Mt = 0; Mt < 2; ++Mt)
                    #pragma unroll
                    for (int r = 0; r < 4; ++r) {
                        float h = acc1[Mt][Nt][r];
                        s[Nt] += h; sq[Nt] += h*h;
                    }
        }

        if constexpr (STAGE >= 2) {
            // Z1 = relu(bn1(H1)) -> trunc-hi / rtne-lo packed
            #pragma unroll
            for (int Mt = 0; Mt < 2; ++Mt)
                #pragma unroll
                for (int Nt = 0; Nt < 4; ++Nt)
                    #pragma unroll
                    for (int r = 0; r < 4; ++r) {
                        float z = fmaxf(fmaf(acc1[Mt][Nt][r], sc1v[Nt], sf1v[Nt]), 0.f);
                        unsigned zu = __float_as_uint(z);
                        float rr = z - __uint_as_float(zu & 0xffff0000u);
                        *(unsigned*)&zw[(Mt*16 + q8*4 + r)*136 + 2*(Nt*16 + ln)] = pk2r(zu, rtneb(rr));
                    }
            LDS_SYNC();

            // GEMM2: 32x64, K=128 (streamed W1 frags)
            float4v acc2[2][4];
            #pragma unroll
            for (int Mt = 0; Mt < 2; ++Mt)
                #pragma unroll
                for (int Nt = 0; Nt < 4; ++Nt)
                    acc2[Mt][Nt] = (float4v){b1v[Nt], b1v[Nt], b1v[Nt], b1v[Nt]};
            #pragma unroll
            for (int Ks = 0; Ks < 4; ++Ks) {
                short8 a2[2];
                #pragma unroll
                for (int Mt = 0; Mt < 2; ++Mt)
                    a2[Mt] = *(const short8*)&zw[(Mt*16 + ln)*136 + Ks*32 + q8*8];
                #pragma unroll
                for (int Nt = 0; Nt < 4; ++Nt) {
                    short8 bf = ldw(w1f, (Nt*4 + Ks)*64 + l);
                    #pragma unroll
                    for (int Mt = 0; Mt < 2; ++Mt)
                        acc2[Mt][Nt] = __builtin_amdgcn_mfma_f32_16x16x32_bf16(
                            a2[Mt], bf, acc2[Mt][Nt], 0, 0, 0);
                }
            }

            if constexpr (STAGE == 2) {
                #pragma unroll
                for (int Nt = 0; Nt < 4; ++Nt)
                    #pragma unroll
                    for (int Mt = 0; Mt < 2; ++Mt)
                        #pragma unroll
                        for (int r = 0; r < 4; ++r) {
                            float h = acc2[Mt][Nt][r];
                            s[Nt] += h; sq[Nt] += h*h;
                        }
            }

            if constexpr (STAGE == 3) {
                LDS_SYNC();
                #pragma unroll
                for (int Mt = 0; Mt < 2; ++Mt)
                    #pragma unroll
                    for (int Nt = 0; Nt < 4; ++Nt)
                        #pragma unroll
                        for (int r = 0; r < 4; ++r) {
                            float z = fmaxf(fmaf(acc2[Mt][Nt][r], sc2v[Nt], sf2v[Nt]), 0.f);
                            unsigned zu = __float_as_uint(z);
                            float rr = z - __uint_as_float(zu & 0xffff0000u);
                            *(unsigned*)&zw[(Mt*16 + q8*4 + r)*136 + 2*(Nt*16 + ln)] = pk2r(zu, rtneb(rr));
                        }
                LDS_SYNC();

                // GEMM3: 32x128, K=128 (streamed W2 frags)
                float4v acc3[2][8];
                #pragma unroll
                for (int Mt = 0; Mt < 2; ++Mt)
                    #pragma unroll
                    for (int Nt = 0; Nt < 8; ++Nt)
                        acc3[Mt][Nt] = (float4v){b2v[Nt], b2v[Nt], b2v[Nt], b2v[Nt]};
                #pragma unroll
                for (int Ks = 0; Ks < 4; ++Ks) {
                    short8 a2[2];
                    #pragma unroll
                    for (int Mt = 0; Mt < 2; ++Mt)
                        a2[Mt] = *(const short8*)&zw[(Mt*16 + ln)*136 + Ks*32 + q8*8];
                    #pragma unroll
                    for (int Nt = 0; Nt < 8; ++Nt) {
                        short8 bf = ldw(w2f, (Nt*4 + Ks)*64 + l);
                        #pragma unroll
                        for (int Mt = 0; Mt < 2; ++Mt)
                            acc3[Mt][Nt] = __builtin_amdgcn_mfma_f32_16x16x32_bf16(
                                a2[Mt], bf, acc3[Mt][Nt], 0, 0, 0);
                    }
                }

                // stats3 + pre-BN max/min pool (pick by sign of gamma2)
                float mm[8];
                #pragma unroll
                for (int Nt = 0; Nt < 8; ++Nt) {
                    const bool pos = g2v[Nt] >= 0.f;
                    float m = acc3[0][Nt][0];
                    #pragma unroll
                    for (int Mt = 0; Mt < 2; ++Mt)
                        #pragma unroll
                        for (int r = 0; r < 4; ++r) {
                            float h = acc3[Mt][Nt][r];
                            s[Nt] += h; sq[Nt] += h*h;
                            if (!(Mt == 0 && r == 0))
                                m = pos ? fmaxf(m, h) : fminf(m, h);
                        }
                    float o = __shfl_xor(m, 16); m = pos ? fmaxf(m, o) : fminf(m, o);
                    o = __shfl_xor(m, 32);       m = pos ? fmaxf(m, o) : fminf(m, o);
                    mm[Nt] = m;
                }
                if (l < 16) {
                    #pragma unroll
                    for (int Nt = 0; Nt < 8; ++Nt)
                        out_pts[(long)g*128 + Nt*16 + l] = mm[Nt];
                }
            }
        }
    }

    // stats: quad-reduce then one atomic burst per wave
    constexpr int NT = (STAGE == 3) ? 8 : 4;
    constexpr int soff = (STAGE == 1) ? 0 : (STAGE == 2) ? 128 : 256;
    constexpr int qoff = (STAGE == 1) ? 64 : (STAGE == 2) ? 192 : 384;
    #pragma unroll
    for (int t = 0; t < NT; ++t) {
        float a = s[t], b = sq[t];
        a += __shfl_xor(a, 16); a += __shfl_xor(a, 32);
        b += __shfl_xor(b, 16); b += __shfl_xor(b, 32);
        if (l < 16) {
            atomicAdd(&sums[soff + t*16 + l], a);
            atomicAdd(&sums[qoff + t*16 + l], b);
        }
    }
}

// ---------------- finalize: mean/var -> BN scale/shift ----------------
__global__ void k_fin(const float* __restrict__ sums, const float* __restrict__ g,
                      const float* __restrict__ be, float* __restrict__ scl,
                      int sum_off, int sq_off, int sc_off, int sh_off, int C)
{
    int c = threadIdx.x;
    if (c < C) {
        float mean = sums[sum_off + c] * (1.0f / PP);
        float var  = sums[sq_off + c] * (1.0f / PP) - mean * mean;
        float s = g[c] * rsqrtf(var + EPSF);
        scl[sc_off + c] = s;
        scl[sh_off + c] = be[c] - mean * s;
    }
}

// ---------------- apply BN3+ReLU to the pooled pre-activations ----------------
__global__ void k_bnmax(float* __restrict__ op, const float* __restrict__ scl) {
    int i = blockIdx.x * 256 + threadIdx.x;
    int c = i & 127;
    float sc = scl[256 + c], sf = scl[384 + c];
    op[i] = fmaxf(fmaf(op[i], sc, sf), 0.f);
}

extern "C" void kernel_launch(void* const* d_in, const int* in_sizes, int n_in,
                              void* d_out, int out_size, void* d_ws, size_t ws_size,
                              hipStream_t stream) {
    const float* xyz = (const float*)d_in[0];
    const float* pts = (const float*)d_in[1];
    const int*   fps = (const int*)d_in[2];
    const float* w0  = (const float*)d_in[3];
    const float* b0  = (const float*)d_in[4];
    const float* g0  = (const float*)d_in[5];
    const float* be0 = (const float*)d_in[6];
    const float* w1  = (const float*)d_in[7];
    const float* b1  = (const float*)d_in[8];
    const float* g1  = (const float*)d_in[9];
    const float* be1 = (const float*)d_in[10];
    const float* w2  = (const float*)d_in[11];
    const float* b2  = (const float*)d_in[12];
    const float* g2  = (const float*)d_in[13];
    const float* be2 = (const float*)d_in[14];

    float* ws = (float*)d_ws;
    float* out_xyz = (float*)d_out;
    float* out_pts = (float*)d_out + NG * 3;

    k_prep<<<1, 256, 0, stream>>>(w0, w1, w2, ws);
    k_select<<<NG / 4, 256, 0, stream>>>(xyz, fps, out_xyz, ws);

    k_pass<1><<<1024, 256, 0, stream>>>(xyz, pts, b0, b1, b2, g2, ws, out_pts);
    k_fin<<<1, 128, 0, stream>>>(ws + WS_SUMS, g0, be0, ws + WS_SCALE, 0, 64, 0, 64, 64);

    k_pass<2><<<1024, 256, 0, stream>>>(xyz, pts, b0, b1, b2, g2, ws, out_pts);
    k_fin<<<1, 128, 0, stream>>>(ws + WS_SUMS, g1, be1, ws + WS_SCALE, 128, 192, 128, 192, 64);

    k_pass<3><<<1024, 256, 0, stream>>>(xyz, pts, b0, b1, b2, g2, ws, out_pts);
    k_fin<<<1, 128, 0, stream>>>(ws + WS_SUMS, g2, be2, ws + WS_SCALE, 256, 384, 256, 384, 128);

    k_bnmax<<<NG * 128 / 256, 256, 0, stream>>>(out_pts, ws + WS_SCALE);
}

// Round 6
// 559.293 us; speedup vs baseline: 10.4687x; 1.8136x over previous
//
#include <hip/hip_runtime.h>
#include <hip/hip_bf16.h>

// All float tensors are fp32 (reference dtypes, bf16-grid values). fps_idx int32.

typedef __attribute__((ext_vector_type(8))) short short8;
typedef __attribute__((ext_vector_type(4))) float float4v;

constexpr int BB = 16, NN = 4096, SS = 1024, DD = 64, KK = 32;
constexpr int PP = BB * SS * KK;            // 524288 grouped points
constexpr int NG = BB * SS;                 // 16384 query groups
constexpr float EPSF = 1e-5f;

// Workspace layout (float offsets).
constexpr int WS_IDX   = 0;                    // ushort[PP]
constexpr int WS_NXYZ  = PP / 2;               // float[NG*3]
constexpr int WS_W0PK  = WS_NXYZ + NG*3;       // ushort[6144]  W0' frag image (K=96: feat + xyz hi/lo)
constexpr int WS_W1PK  = WS_W0PK + 3072;       // ushort[4096]  W1' frag image (K=64, bf16-only)
constexpr int WS_W2PK  = WS_W1PK + 2048;       // ushort[8192]  W2' frag image (K=64, bf16-only)
constexpr int WS_W1PKD = WS_W2PK + 4096;       // ushort[8192]  W1 dup image (K=128 hi/lo, fallback)
constexpr int WS_W2PKD = WS_W1PKD + 4096;      // ushort[16384] W2 dup image (K=128 hi/lo, fallback)
constexpr int WS_SUMS  = WS_W2PKD + 8192;      // float[512]
constexpr int WS_SCALE = WS_SUMS + 512;        // float[512]
constexpr int WS_H1    = WS_SCALE + 512;       // ushort[PP*64] pre-BN H1 (bf16)
constexpr int WS_H2    = WS_H1 + PP*32;        // ushort[PP*64] pre-BN H2 (bf16)
constexpr int WS_END   = WS_H2 + PP*32;
constexpr size_t WS_FAST_BYTES = (size_t)WS_END * 4;

__device__ __forceinline__ unsigned rtne16(float x) {
    unsigned b = __float_as_uint(x);
    return (b + 0x7fffu + ((b >> 16) & 1u)) >> 16;
}
// bf16 RTNE bits left in [31:16]
__device__ __forceinline__ unsigned rtneb(float r) {
    unsigned b = __float_as_uint(r);
    return b + 0x7fffu + ((b >> 16) & 1u);
}
// pack: low16 = a[31:16], high16 = b[31:16]
__device__ __forceinline__ unsigned pk2r(unsigned a, unsigned b) {
    return __builtin_amdgcn_perm(a, b, 0x03020706u);
}
__device__ __forceinline__ unsigned pk2f(float a, float b) {
    return pk2r(__float_as_uint(a), __float_as_uint(b));
}
// unpack bf16 pair, apply BN+ReLU per element, repack to bf16 pair
__device__ __forceinline__ unsigned bnpack(unsigned u, float sce, float sfe,
                                           float sco, float sfo) {
    float fe = __uint_as_float(u << 16);
    float fo = __uint_as_float(u & 0xffff0000u);
    float ze = fmaxf(fmaf(fe, sce, sfe), 0.f);
    float zo = fmaxf(fmaf(fo, sco, sfo), 0.f);
    return pk2r(rtneb(ze), rtneb(zo));
}

union UF { uint4 u; short8 s; };
__device__ __forceinline__ short8 ldw(const uint4* __restrict__ p, int idx) {
    UF u; u.u = p[idx]; return u.s;
}

#define LDS_SYNC() asm volatile("s_waitcnt lgkmcnt(0)" ::: "memory")

// ---------------- prep: frag-major bf16 weight images + zero stats ----------------
__global__ void k_prep(const float* __restrict__ w0, const float* __restrict__ w1,
                       const float* __restrict__ w2, float* __restrict__ ws) {
    const int t = threadIdx.x;
    ushort* w0pk = (ushort*)(ws + WS_W0PK);
    for (int i = t; i < 6144; i += 256) {        // [Nt(4)][Ks(3)][lane(64)][j(8)]
        int j = i & 7, l = (i >> 3) & 63, Ks = (i >> 9) % 3, Nt = i / 1536;
        int o = Nt*16 + (l & 15);
        int k = Ks*32 + (l >> 4)*8 + j;
        float v = 0.f;
        if (k < 64)      v = w0[o*67 + 3 + k];
        else if (k < 67) v = w0[o*67 + (k - 64)];     // xyz hi
        else if (k < 70) v = w0[o*67 + (k - 67)];     // xyz lo (same weights)
        w0pk[i] = (ushort)rtne16(v);
    }
    ushort* w1pk = (ushort*)(ws + WS_W1PK);
    for (int i = t; i < 4096; i += 256) {        // [Nt(4)][Ks(2)][lane][j], K=64
        int j = i & 7, l = (i >> 3) & 63, Ks = (i >> 9) & 1, Nt = i >> 10;
        int o = Nt*16 + (l & 15);
        int k = Ks*32 + (l >> 4)*8 + j;
        w1pk[i] = (ushort)rtne16(w1[o*64 + k]);
    }
    ushort* w2pk = (ushort*)(ws + WS_W2PK);
    for (int i = t; i < 8192; i += 256) {        // [Nt(8)][Ks(2)][lane][j], K=64
        int j = i & 7, l = (i >> 3) & 63, Ks = (i >> 9) & 1, Nt = i >> 10;
        int o = Nt*16 + (l & 15);
        int k = Ks*32 + (l >> 4)*8 + j;
        w2pk[i] = (ushort)rtne16(w2[o*64 + k]);
    }
    // fallback dup images (K=128 hi/lo interleaved)
    ushort* w1pd = (ushort*)(ws + WS_W1PKD);
    for (int i = t; i < 8192; i += 256) {        // [Nt(4)][Ks(4)][lane][j]
        int j = i & 7, l = (i >> 3) & 63, Ks = (i >> 9) & 3, Nt = i >> 11;
        int o = Nt*16 + (l & 15);
        int c = (Ks*32 + (l >> 4)*8 + j) >> 1;
        w1pd[i] = (ushort)rtne16(w1[o*64 + c]);
    }
    ushort* w2pd = (ushort*)(ws + WS_W2PKD);
    for (int i = t; i < 16384; i += 256) {       // [Nt(8)][Ks(4)][lane][j]
        int j = i & 7, l = (i >> 3) & 63, Ks = (i >> 9) & 3, Nt = i >> 11;
        int o = Nt*16 + (l & 15);
        int c = (Ks*32 + (l >> 4)*8 + j) >> 1;
        w2pd[i] = (ushort)rtne16(w2[o*64 + c]);
    }
    for (int i = t; i < 512; i += 256) ws[WS_SUMS + i] = 0.f;
}

// ---------------- select: exact top-32 nearest neighbors per query ----------------
__global__ __launch_bounds__(256, 2) void k_select(
    const float* __restrict__ xyz, const int* __restrict__ fps,
    float* __restrict__ out_xyz, float* __restrict__ ws)
{
    __shared__ float sx[NN], sy[NN], sz[NN];
    const int tid = threadIdx.x;
    const int qb = blockIdx.x * 4;
    const int b  = qb >> 10;
    const float* xb = xyz + (long)b * NN * 3;
    for (int i = tid; i < NN; i += 256) {
        sx[i] = xb[i*3 + 0];
        sy[i] = xb[i*3 + 1];
        sz[i] = xb[i*3 + 2];
    }
    __syncthreads();

    const int wave = tid >> 6, lane = tid & 63;
    const int q = qb + wave;
    const int nq = fps[q];
    const float qx = sx[nq], qy = sy[nq], qz = sz[nq];
    const float qw = __fadd_rn(__fadd_rn(__fmul_rn(qx,qx), __fmul_rn(qy,qy)), __fmul_rn(qz,qz));

    float* nxyz = ws + WS_NXYZ;
    unsigned short* idx_ws = (unsigned short*)ws;
    if (lane < 3) {
        float v = (lane == 0) ? qx : ((lane == 1) ? qy : qz);
        out_xyz[q*3 + lane] = v;
        nxyz[q*3 + lane] = v;
    }

    unsigned key[64];
    unsigned kmin = 0xFFFFFFFFu, kmax = 0u;
    #pragma unroll
    for (int i = 0; i < 64; ++i) {
        const int n = i*64 + lane;
        const float px = sx[n], py = sy[n], pz = sz[n];
        const float pw = __fadd_rn(__fadd_rn(__fmul_rn(px,px), __fmul_rn(py,py)), __fmul_rn(pz,pz));
        float dot = fmaf(qx, px, 0.f);
        dot = fmaf(qy, py, dot);
        dot = fmaf(qz, pz, dot);
        float d = __fadd_rn(__fadd_rn(__fmul_rn(-2.0f, dot), qw), pw);
        unsigned u = __float_as_uint(d);
        unsigned k = u ^ (unsigned)(((int)u >> 31) | 0x80000000);
        key[i] = k;
        kmin = min(kmin, k); kmax = max(kmax, k);
    }
    #pragma unroll
    for (int off = 32; off > 0; off >>= 1) {
        kmin = min(kmin, (unsigned)__shfl_xor((int)kmin, off));
        kmax = max(kmax, (unsigned)__shfl_xor((int)kmax, off));
    }

    unsigned lo = kmin, hi = kmax;
    while (lo < hi) {
        unsigned mid = lo + ((hi - lo) >> 1);
        int c = 0;
        #pragma unroll
        for (int i = 0; i < 64; ++i)
            c += (int)__popcll(__ballot(key[i] <= mid));
        if (c >= 32) hi = mid; else lo = mid + 1;
    }
    const unsigned T = lo;

    const unsigned long long lmask = (1ull << lane) - 1ull;
    int cnt = 0;
    const int base = q * KK;
    #pragma unroll
    for (int i = 0; i < 64; ++i) {
        bool pr = key[i] < T;
        unsigned long long m = __ballot(pr);
        if (pr) idx_ws[base + cnt + (int)__popcll(m & lmask)] = (unsigned short)(i*64 + lane);
        cnt += (int)__popcll(m);
    }
    for (int i = 0; i < 64 && cnt < KK; ++i) {
        bool pr = key[i] == T;
        unsigned long long m = __ballot(pr);
        int pos = cnt + (int)__popcll(m & lmask);
        if (pr && pos < KK) idx_ws[base + pos] = (unsigned short)(i*64 + lane);
        cnt += (int)__popcll(m);
    }
}

// ================= fast path: materialized pre-BN activations =================
// H layout: ushort bf16 H[p][c], p = grouped point (g*32 + m). A-frag reads and
// C-writes are coalesced; no LDS roundtrip, no recompute.

// ---- pass A: gather + GEMM1 -> H1 + stats1 ----
__global__ __launch_bounds__(256, 2) void k_g1(
    const float* __restrict__ xyz, const float* __restrict__ pts,
    const float* __restrict__ b0, float* __restrict__ ws,
    ushort* __restrict__ h1)
{
    __shared__ float rbuf[4][128];
    const int tid = threadIdx.x;
    const int wv = tid >> 6, l = tid & 63, ln = l & 15, q8 = l >> 4;

    const ushort* idxw = (const ushort*)ws;
    const float* nxyz = ws + WS_NXYZ;
    float* sums = ws + WS_SUMS;
    const uint4* w0f = (const uint4*)(ws + WS_W0PK);

    short8 w0r[12];
    #pragma unroll
    for (int t = 0; t < 12; ++t) w0r[t] = ldw(w0f, t*64 + l);
    float b0v[4];
    #pragma unroll
    for (int n = 0; n < 4; ++n) b0v[n] = b0[n*16 + ln];

    float s[4] = {0,0,0,0}, sq[4] = {0,0,0,0};
    const int gbase = blockIdx.x*4 + wv;

    for (int it = 0; it < 4; ++it) {
        const int g = gbase + it*4096;
        const float nqx = nxyz[g*3+0], nqy = nxyz[g*3+1], nqz = nxyz[g*3+2];

        short8 a1[2][3];
        #pragma unroll
        for (int Mt = 0; Mt < 2; ++Mt) {
            int nb = idxw[g*32 + Mt*16 + ln];
            int row = (g >> 10)*NN + nb;
            const float* p = pts + row*64 + q8*8;
            float4 f0 = *(const float4*)p;
            float4 f1 = *(const float4*)(p + 4);
            float4 f2 = *(const float4*)(p + 32);
            float4 f3 = *(const float4*)(p + 36);
            UF t0, t1;
            t0.u.x = pk2f(f0.x, f0.y); t0.u.y = pk2f(f0.z, f0.w);
            t0.u.z = pk2f(f1.x, f1.y); t0.u.w = pk2f(f1.z, f1.w);
            a1[Mt][0] = t0.s;
            t1.u.x = pk2f(f2.x, f2.y); t1.u.y = pk2f(f2.z, f2.w);
            t1.u.z = pk2f(f3.x, f3.y); t1.u.w = pk2f(f3.z, f3.w);
            a1[Mt][1] = t1.s;
            UF x; x.u = make_uint4(0,0,0,0);
            if (q8 == 0) {
                float vx = xyz[row*3+0] - nqx;
                float vy = xyz[row*3+1] - nqy;
                float vz = xyz[row*3+2] - nqz;
                unsigned bx = __float_as_uint(vx), by = __float_as_uint(vy), bz = __float_as_uint(vz);
                float rx = vx - __uint_as_float(bx & 0xffff0000u);
                float ry = vy - __uint_as_float(by & 0xffff0000u);
                float rz = vz - __uint_as_float(bz & 0xffff0000u);
                x.u.x = pk2r(bx, by);
                x.u.y = pk2r(bz, rtneb(rx));
                x.u.z = pk2r(rtneb(ry), rtneb(rz));
            }
            a1[Mt][2] = x.s;
        }

        float4v acc[2][4];
        #pragma unroll
        for (int Mt = 0; Mt < 2; ++Mt)
            #pragma unroll
            for (int Nt = 0; Nt < 4; ++Nt)
                acc[Mt][Nt] = (float4v){b0v[Nt], b0v[Nt], b0v[Nt], b0v[Nt]};
        #pragma unroll
        for (int Ks = 0; Ks < 3; ++Ks)
            #pragma unroll
            for (int Nt = 0; Nt < 4; ++Nt)
                #pragma unroll
                for (int Mt = 0; Mt < 2; ++Mt)
                    acc[Mt][Nt] = __builtin_amdgcn_mfma_f32_16x16x32_bf16(
                        a1[Mt][Ks], w0r[Nt*3 + Ks], acc[Mt][Nt], 0, 0, 0);

        #pragma unroll
        for (int Mt = 0; Mt < 2; ++Mt)
            #pragma unroll
            for (int Nt = 0; Nt < 4; ++Nt)
                #pragma unroll
                for (int r = 0; r < 4; ++r) {
                    float h = acc[Mt][Nt][r];
                    s[Nt] += h; sq[Nt] += h*h;
                    h1[(g*32 + Mt*16 + q8*4 + r)*64 + Nt*16 + ln] = (ushort)rtne16(h);
                }
    }

    #pragma unroll
    for (int t = 0; t < 4; ++t) {
        float a = s[t], b = sq[t];
        a += __shfl_xor(a, 16); a += __shfl_xor(a, 32);
        b += __shfl_xor(b, 16); b += __shfl_xor(b, 32);
        if (l < 16) { rbuf[wv][t*16 + l] = a; rbuf[wv][64 + t*16 + l] = b; }
    }
    __syncthreads();
    if (wv == 0 && l < 16) {
        #pragma unroll
        for (int t = 0; t < 4; ++t) {
            float a = rbuf[0][t*16+l] + rbuf[1][t*16+l] + rbuf[2][t*16+l] + rbuf[3][t*16+l];
            float b = rbuf[0][64+t*16+l] + rbuf[1][64+t*16+l] + rbuf[2][64+t*16+l] + rbuf[3][64+t*16+l];
            atomicAdd(&sums[t*16 + l], a);
            atomicAdd(&sums[64 + t*16 + l], b);
        }
    }
}

// ---- pass B: H1 -> BN1+ReLU -> GEMM2 -> H2 + stats2 ----
__global__ __launch_bounds__(256, 2) void k_g2(
    const float* __restrict__ b1, float* __restrict__ ws,
    const ushort* __restrict__ h1, ushort* __restrict__ h2)
{
    __shared__ float rbuf[4][128];
    const int tid = threadIdx.x;
    const int wv = tid >> 6, l = tid & 63, ln = l & 15, q8 = l >> 4;

    const float* scl = ws + WS_SCALE;
    float* sums = ws + WS_SUMS;
    const uint4* w1f = (const uint4*)(ws + WS_W1PK);

    float b1v[4];
    #pragma unroll
    for (int n = 0; n < 4; ++n) b1v[n] = b1[n*16 + ln];
    float4 sc[2][2], sf[2][2];
    #pragma unroll
    for (int Ks = 0; Ks < 2; ++Ks) {
        sc[Ks][0] = *(const float4*)&scl[Ks*32 + q8*8];
        sc[Ks][1] = *(const float4*)&scl[Ks*32 + q8*8 + 4];
        sf[Ks][0] = *(const float4*)&scl[64 + Ks*32 + q8*8];
        sf[Ks][1] = *(const float4*)&scl[64 + Ks*32 + q8*8 + 4];
    }

    float s[4] = {0,0,0,0}, sq[4] = {0,0,0,0};
    const int gbase = blockIdx.x*4 + wv;

    for (int it = 0; it < 4; ++it) {
        const int g = gbase + it*4096;

        short8 a[2][2];
        #pragma unroll
        for (int Mt = 0; Mt < 2; ++Mt)
            #pragma unroll
            for (int Ks = 0; Ks < 2; ++Ks) {
                uint4 hv = *(const uint4*)&h1[(g*32 + Mt*16 + ln)*64 + Ks*32 + q8*8];
                UF t;
                t.u.x = bnpack(hv.x, sc[Ks][0].x, sf[Ks][0].x, sc[Ks][0].y, sf[Ks][0].y);
                t.u.y = bnpack(hv.y, sc[Ks][0].z, sf[Ks][0].z, sc[Ks][0].w, sf[Ks][0].w);
                t.u.z = bnpack(hv.z, sc[Ks][1].x, sf[Ks][1].x, sc[Ks][1].y, sf[Ks][1].y);
                t.u.w = bnpack(hv.w, sc[Ks][1].z, sf[Ks][1].z, sc[Ks][1].w, sf[Ks][1].w);
                a[Mt][Ks] = t.s;
            }

        float4v acc[2][4];
        #pragma unroll
        for (int Mt = 0; Mt < 2; ++Mt)
            #pragma unroll
            for (int Nt = 0; Nt < 4; ++Nt)
                acc[Mt][Nt] = (float4v){b1v[Nt], b1v[Nt], b1v[Nt], b1v[Nt]};
        #pragma unroll
        for (int Ks = 0; Ks < 2; ++Ks)
            #pragma unroll
            for (int Nt = 0; Nt < 4; ++Nt) {
                short8 bf = ldw(w1f, (Nt*2 + Ks)*64 + l);
                #pragma unroll
                for (int Mt = 0; Mt < 2; ++Mt)
                    acc[Mt][Nt] = __builtin_amdgcn_mfma_f32_16x16x32_bf16(
                        a[Mt][Ks], bf, acc[Mt][Nt], 0, 0, 0);
            }

        #pragma unroll
        for (int Mt = 0; Mt < 2; ++Mt)
            #pragma unroll
            for (int Nt = 0; Nt < 4; ++Nt)
                #pragma unroll
                for (int r = 0; r < 4; ++r) {
                    float h = acc[Mt][Nt][r];
                    s[Nt] += h; sq[Nt] += h*h;
                    h2[(g*32 + Mt*16 + q8*4 + r)*64 + Nt*16 + ln] = (ushort)rtne16(h);
                }
    }

    #pragma unroll
    for (int t = 0; t < 4; ++t) {
        float a = s[t], b = sq[t];
        a += __shfl_xor(a, 16); a += __shfl_xor(a, 32);
        b += __shfl_xor(b, 16); b += __shfl_xor(b, 32);
        if (l < 16) { rbuf[wv][t*16 + l] = a; rbuf[wv][64 + t*16 + l] = b; }
    }
    __syncthreads();
    if (wv == 0 && l < 16) {
        #pragma unroll
        for (int t = 0; t < 4; ++t) {
            float a = rbuf[0][t*16+l] + rbuf[1][t*16+l] + rbuf[2][t*16+l] + rbuf[3][t*16+l];
            float b = rbuf[0][64+t*16+l] + rbuf[1][64+t*16+l] + rbuf[2][64+t*16+l] + rbuf[3][64+t*16+l];
            atomicAdd(&sums[128 + t*16 + l], a);
            atomicAdd(&sums[192 + t*16 + l], b);
        }
    }
}

// ---- pass C: H2 -> BN2+ReLU -> GEMM3 -> stats3 + pre-BN pool -> out ----
__global__ __launch_bounds__(256, 2) void k_g3(
    const float* __restrict__ b2, const float* __restrict__ g2,
    float* __restrict__ ws, const ushort* __restrict__ h2,
    float* __restrict__ out_pts)
{
    __shared__ float rbuf[4][256];
    const int tid = threadIdx.x;
    const int wv = tid >> 6, l = tid & 63, ln = l & 15, q8 = l >> 4;

    const float* scl = ws + WS_SCALE;
    float* sums = ws + WS_SUMS;
    const uint4* w2f = (const uint4*)(ws + WS_W2PK);

    float b2v[8], g2v[8];
    #pragma unroll
    for (int n = 0; n < 8; ++n) { b2v[n] = b2[n*16 + ln]; g2v[n] = g2[n*16 + ln]; }
    float4 sc[2][2], sf[2][2];
    #pragma unroll
    for (int Ks = 0; Ks < 2; ++Ks) {
        sc[Ks][0] = *(const float4*)&scl[128 + Ks*32 + q8*8];
        sc[Ks][1] = *(const float4*)&scl[128 + Ks*32 + q8*8 + 4];
        sf[Ks][0] = *(const float4*)&scl[192 + Ks*32 + q8*8];
        sf[Ks][1] = *(const float4*)&scl[192 + Ks*32 + q8*8 + 4];
    }

    float s[8] = {0,0,0,0,0,0,0,0}, sq[8] = {0,0,0,0,0,0,0,0};
    const int gbase = blockIdx.x*4 + wv;

    for (int it = 0; it < 4; ++it) {
        const int g = gbase + it*4096;

        short8 a[2][2];
        #pragma unroll
        for (int Mt = 0; Mt < 2; ++Mt)
            #pragma unroll
            for (int Ks = 0; Ks < 2; ++Ks) {
                uint4 hv = *(const uint4*)&h2[(g*32 + Mt*16 + ln)*64 + Ks*32 + q8*8];
                UF t;
                t.u.x = bnpack(hv.x, sc[Ks][0].x, sf[Ks][0].x, sc[Ks][0].y, sf[Ks][0].y);
                t.u.y = bnpack(hv.y, sc[Ks][0].z, sf[Ks][0].z, sc[Ks][0].w, sf[Ks][0].w);
                t.u.z = bnpack(hv.z, sc[Ks][1].x, sf[Ks][1].x, sc[Ks][1].y, sf[Ks][1].y);
                t.u.w = bnpack(hv.w, sc[Ks][1].z, sf[Ks][1].z, sc[Ks][1].w, sf[Ks][1].w);
                a[Mt][Ks] = t.s;
            }

        float4v acc[2][8];
        #pragma unroll
        for (int Mt = 0; Mt < 2; ++Mt)
            #pragma unroll
            for (int Nt = 0; Nt < 8; ++Nt)
                acc[Mt][Nt] = (float4v){b2v[Nt], b2v[Nt], b2v[Nt], b2v[Nt]};
        #pragma unroll
        for (int Ks = 0; Ks < 2; ++Ks)
            #pragma unroll
            for (int Nt = 0; Nt < 8; ++Nt) {
                short8 bf = ldw(w2f, (Nt*2 + Ks)*64 + l);
                #pragma unroll
                for (int Mt = 0; Mt < 2; ++Mt)
                    acc[Mt][Nt] = __builtin_amdgcn_mfma_f32_16x16x32_bf16(
                        a[Mt][Ks], bf, acc[Mt][Nt], 0, 0, 0);
            }

        float mm[8];
        #pragma unroll
        for (int Nt = 0; Nt < 8; ++Nt) {
            const bool pos = g2v[Nt] >= 0.f;
            float m = acc[0][Nt][0];
            #pragma unroll
            for (int Mt = 0; Mt < 2; ++Mt)
                #pragma unroll
                for (int r = 0; r < 4; ++r) {
                    float h = acc[Mt][Nt][r];
                    s[Nt] += h; sq[Nt] += h*h;
                    if (!(Mt == 0 && r == 0))
                        m = pos ? fmaxf(m, h) : fminf(m, h);
                }
            float o = __shfl_xor(m, 16); m = pos ? fmaxf(m, o) : fminf(m, o);
            o = __shfl_xor(m, 32);       m = pos ? fmaxf(m, o) : fminf(m, o);
            mm[Nt] = m;
        }
        if (l < 16) {
            #pragma unroll
            for (int Nt = 0; Nt < 8; ++Nt)
                out_pts[(long)g*128 + Nt*16 + l] = mm[Nt];
        }
    }

    #pragma unroll
    for (int t = 0; t < 8; ++t) {
        float a = s[t], b = sq[t];
        a += __shfl_xor(a, 16); a += __shfl_xor(a, 32);
        b += __shfl_xor(b, 16); b += __shfl_xor(b, 32);
        if (l < 16) { rbuf[wv][t*16 + l] = a; rbuf[wv][128 + t*16 + l] = b; }
    }
    __syncthreads();
    if (wv == 0 && l < 16) {
        #pragma unroll
        for (int t = 0; t < 8; ++t) {
            float a = rbuf[0][t*16+l] + rbuf[1][t*16+l] + rbuf[2][t*16+l] + rbuf[3][t*16+l];
            float b = rbuf[0][128+t*16+l] + rbuf[1][128+t*16+l] + rbuf[2][128+t*16+l] + rbuf[3][128+t*16+l];
            atomicAdd(&sums[256 + t*16 + l], a);
            atomicAdd(&sums[384 + t*16 + l], b);
        }
    }
}

// ================= fallback path (small ws): recompute, R4-style =================
template<int STAGE>
__global__ __launch_bounds__(256, 2) void k_passF(
    const float* __restrict__ xyz, const float* __restrict__ pts,
    const float* __restrict__ b0, const float* __restrict__ b1,
    const float* __restrict__ b2, const float* __restrict__ g2,
    float* __restrict__ ws, float* __restrict__ out_pts)
{
    __shared__ __align__(16) ushort zb[(STAGE >= 2) ? 4*32*136 : 8];
    const int tid = threadIdx.x;
    const int wv = tid >> 6, l = tid & 63, ln = l & 15, q8 = l >> 4;
    ushort* zw = &zb[(STAGE >= 2) ? wv*32*136 : 0];

    const ushort* idxw = (const ushort*)ws;
    const float* nxyz = ws + WS_NXYZ;
    const float* scl  = ws + WS_SCALE;
    float*       sums = ws + WS_SUMS;
    const uint4* w0f = (const uint4*)(ws + WS_W0PK);
    const uint4* w1f = (const uint4*)(ws + WS_W1PKD);
    const uint4* w2f = (const uint4*)(ws + WS_W2PKD);

    float b0v[4];
    #pragma unroll
    for (int n = 0; n < 4; ++n) b0v[n] = b0[n*16 + ln];
    float sc1v[4], sf1v[4], b1v[4];
    if constexpr (STAGE >= 2) {
        #pragma unroll
        for (int n = 0; n < 4; ++n) {
            sc1v[n] = scl[n*16 + ln]; sf1v[n] = scl[64 + n*16 + ln];
            b1v[n] = b1[n*16 + ln];
        }
    }
    float sc2v[4], sf2v[4], b2v[8], g2v[8];
    if constexpr (STAGE >= 3) {
        #pragma unroll
        for (int n = 0; n < 4; ++n) {
            sc2v[n] = scl[128 + n*16 + ln]; sf2v[n] = scl[192 + n*16 + ln];
        }
        #pragma unroll
        for (int n = 0; n < 8; ++n) { b2v[n] = b2[n*16 + ln]; g2v[n] = g2[n*16 + ln]; }
    }

    float s[8] = {0,0,0,0,0,0,0,0}, sq[8] = {0,0,0,0,0,0,0,0};

    for (int g = blockIdx.x*4 + wv; g < NG; g += 4096) {
        const float nqx = nxyz[g*3+0], nqy = nxyz[g*3+1], nqz = nxyz[g*3+2];
        short8 a1[2][3];
        #pragma unroll
        for (int Mt = 0; Mt < 2; ++Mt) {
            int nb = idxw[g*32 + Mt*16 + ln];
            int row = (g >> 10)*NN + nb;
            const float* p = pts + row*64 + q8*8;
            float4 f0 = *(const float4*)p, f1 = *(const float4*)(p + 4);
            float4 f2 = *(const float4*)(p + 32), f3 = *(const float4*)(p + 36);
            UF t0, t1;
            t0.u.x = pk2f(f0.x, f0.y); t0.u.y = pk2f(f0.z, f0.w);
            t0.u.z = pk2f(f1.x, f1.y); t0.u.w = pk2f(f1.z, f1.w);
            a1[Mt][0] = t0.s;
            t1.u.x = pk2f(f2.x, f2.y); t1.u.y = pk2f(f2.z, f2.w);
            t1.u.z = pk2f(f3.x, f3.y); t1.u.w = pk2f(f3.z, f3.w);
            a1[Mt][1] = t1.s;
            UF x; x.u = make_uint4(0,0,0,0);
            if (q8 == 0) {
                float vx = xyz[row*3+0] - nqx, vy = xyz[row*3+1] - nqy, vz = xyz[row*3+2] - nqz;
                unsigned bx = __float_as_uint(vx), by = __float_as_uint(vy), bz = __float_as_uint(vz);
                float rx = vx - __uint_as_float(bx & 0xffff0000u);
                float ry = vy - __uint_as_float(by & 0xffff0000u);
                float rz = vz - __uint_as_float(bz & 0xffff0000u);
                x.u.x = pk2r(bx, by);
                x.u.y = pk2r(bz, rtneb(rx));
                x.u.z = pk2r(rtneb(ry), rtneb(rz));
            }
            a1[Mt][2] = x.s;
        }

        float4v acc1[2][4];
        #pragma unroll
        for (int Mt = 0; Mt < 2; ++Mt)
            #pragma unroll
            for (int Nt = 0; Nt < 4; ++Nt)
                acc1[Mt][Nt] = (float4v){b0v[Nt], b0v[Nt], b0v[Nt], b0v[Nt]};
        #pragma unroll
        for (int Ks = 0; Ks < 3; ++Ks)
            #pragma unroll
            for (int Nt = 0; Nt < 4; ++Nt) {
                short8 bf = ldw(w0f, (Nt*3 + Ks)*64 + l);
                #pragma unroll
                for (int Mt = 0; Mt < 2; ++Mt)
                    acc1[Mt][Nt] = __builtin_amdgcn_mfma_f32_16x16x32_bf16(
                        a1[Mt][Ks], bf, acc1[Mt][Nt], 0, 0, 0);
            }

        if constexpr (STAGE == 1) {
            #pragma unroll
            for (int Nt = 0; Nt < 4; ++Nt)
                #pragma unroll
                for (int Mt = 0; Mt < 2; ++Mt)
                    #pragma unroll
                    for (int r = 0; r < 4; ++r) {
                        float h = acc1[Mt][Nt][r];
                        s[Nt] += h; sq[Nt] += h*h;
                    }
        }

        if constexpr (STAGE >= 2) {
            #pragma unroll
            for (int Mt = 0; Mt < 2; ++Mt)
                #pragma unroll
                for (int Nt = 0; Nt < 4; ++Nt)
                    #pragma unroll
                    for (int r = 0; r < 4; ++r) {
                        float z = fmaxf(fmaf(acc1[Mt][Nt][r], sc1v[Nt], sf1v[Nt]), 0.f);
                        unsigned zu = __float_as_uint(z);
                        float rr = z - __uint_as_float(zu & 0xffff0000u);
                        *(unsigned*)&zw[(Mt*16 + q8*4 + r)*136 + 2*(Nt*16 + ln)] = pk2r(zu, rtneb(rr));
                    }
            LDS_SYNC();

            float4v acc2[2][4];
            #pragma unroll
            for (int Mt = 0; Mt < 2; ++Mt)
                #pragma unroll
                for (int Nt = 0; Nt < 4; ++Nt)
                    acc2[Mt][Nt] = (float4v){b1v[Nt], b1v[Nt], b1v[Nt], b1v[Nt]};
            #pragma unroll
            for (int Ks = 0; Ks < 4; ++Ks) {
                short8 a2[2];
                #pragma unroll
                for (int Mt = 0; Mt < 2; ++Mt)
                    a2[Mt] = *(const short8*)&zw[(Mt*16 + ln)*136 + Ks*32 + q8*8];
                #pragma unroll
                for (int Nt = 0; Nt < 4; ++Nt) {
                    short8 bf = ldw(w1f, (Nt*4 + Ks)*64 + l);
                    #pragma unroll
                    for (int Mt = 0; Mt < 2; ++Mt)
                        acc2[Mt][Nt] = __builtin_amdgcn_mfma_f32_16x16x32_bf16(
                            a2[Mt], bf, acc2[Mt][Nt], 0, 0, 0);
                }
            }

            if constexpr (STAGE == 2) {
                #pragma unroll
                for (int Nt = 0; Nt < 4; ++Nt)
                    #pragma unroll
                    for (int Mt = 0; Mt < 2; ++Mt)
                        #pragma unroll
                        for (int r = 0; r < 4; ++r) {
                            float h = acc2[Mt][Nt][r];
                            s[Nt] += h; sq[Nt] += h*h;
                        }
            }

            if constexpr (STAGE == 3) {
                LDS_SYNC();
                #pragma unroll
                for (int Mt = 0; Mt < 2; ++Mt)
                    #pragma unroll
                    for (int Nt = 0; Nt < 4; ++Nt)
                        #pragma unroll
                        for (int r = 0; r < 4; ++r) {
                            float z = fmaxf(fmaf(acc2[Mt][Nt][r], sc2v[Nt], sf2v[Nt]), 0.f);
                            unsigned zu = __float_as_uint(z);
                            float rr = z - __uint_as_float(zu & 0xffff0000u);
                            *(unsigned*)&zw[(Mt*16 + q8*4 + r)*136 + 2*(Nt*16 + ln)] = pk2r(zu, rtneb(rr));
                        }
                LDS_SYNC();

                float4v acc3[2][8];
                #pragma unroll
                for (int Mt = 0; Mt < 2; ++Mt)
                    #pragma unroll
                    for (int Nt = 0; Nt < 8; ++Nt)
                        acc3[Mt][Nt] = (float4v){b2v[Nt], b2v[Nt], b2v[Nt], b2v[Nt]};
                #pragma unroll
                for (int Ks = 0; Ks < 4; ++Ks) {
                    short8 a2[2];
                    #pragma unroll
                    for (int Mt = 0; Mt < 2; ++Mt)
                        a2[Mt] = *(const short8*)&zw[(Mt*16 + ln)*136 + Ks*32 + q8*8];
                    #pragma unroll
                    for (int Nt = 0; Nt < 8; ++Nt) {
                        short8 bf = ldw(w2f, (Nt*4 + Ks)*64 + l);
                        #pragma unroll
                        for (int Mt = 0; Mt < 2; ++Mt)
                            acc3[Mt][Nt] = __builtin_amdgcn_mfma_f32_16x16x32_bf16(
                                a2[Mt], bf, acc3[Mt][Nt], 0, 0, 0);
                    }
                }

                float mm[8];
                #pragma unroll
                for (int Nt = 0; Nt < 8; ++Nt) {
                    const bool pos = g2v[Nt] >= 0.f;
                    float m = acc3[0][Nt][0];
                    #pragma unroll
                    for (int Mt = 0; Mt < 2; ++Mt)
                        #pragma unroll
                        for (int r = 0; r < 4; ++r) {
                            float h = acc3[Mt][Nt][r];
                            s[Nt] += h; sq[Nt] += h*h;
                            if (!(Mt == 0 && r == 0))
                                m = pos ? fmaxf(m, h) : fminf(m, h);
                        }
                    float o = __shfl_xor(m, 16); m = pos ? fmaxf(m, o) : fminf(m, o);
                    o = __shfl_xor(m, 32);       m = pos ? fmaxf(m, o) : fminf(m, o);
                    mm[Nt] = m;
                }
                if (l < 16) {
                    #pragma unroll
                    for (int Nt = 0; Nt < 8; ++Nt)
                        out_pts[(long)g*128 + Nt*16 + l] = mm[Nt];
                }
            }
        }
    }

    constexpr int NT = (STAGE == 3) ? 8 : 4;
    constexpr int soff = (STAGE == 1) ? 0 : (STAGE == 2) ? 128 : 256;
    constexpr int qoff = (STAGE == 1) ? 64 : (STAGE == 2) ? 192 : 384;
    #pragma unroll
    for (int t = 0; t < NT; ++t) {
        float a = s[t], b = sq[t];
        a += __shfl_xor(a, 16); a += __shfl_xor(a, 32);
        b += __shfl_xor(b, 16); b += __shfl_xor(b, 32);
        if (l < 16) {
            atomicAdd(&sums[soff + t*16 + l], a);
            atomicAdd(&sums[qoff + t*16 + l], b);
        }
    }
}

// ---------------- finalize: mean/var -> BN scale/shift ----------------
__global__ void k_fin(const float* __restrict__ sums, const float* __restrict__ g,
                      const float* __restrict__ be, float* __restrict__ scl,
                      int sum_off, int sq_off, int sc_off, int sh_off, int C)
{
    int c = threadIdx.x;
    if (c < C) {
        float mean = sums[sum_off + c] * (1.0f / PP);
        float var  = sums[sq_off + c] * (1.0f / PP) - mean * mean;
        float s = g[c] * rsqrtf(var + EPSF);
        scl[sc_off + c] = s;
        scl[sh_off + c] = be[c] - mean * s;
    }
}

// ---------------- apply BN3+ReLU to the pooled pre-activations ----------------
__global__ void k_bnmax(float* __restrict__ op, const float* __restrict__ scl) {
    int i = blockIdx.x * 256 + threadIdx.x;
    int c = i & 127;
    float sc = scl[256 + c], sf = scl[384 + c];
    op[i] = fmaxf(fmaf(op[i], sc, sf), 0.f);
}

extern "C" void kernel_launch(void* const* d_in, const int* in_sizes, int n_in,
                              void* d_out, int out_size, void* d_ws, size_t ws_size,
                              hipStream_t stream) {
    const float* xyz = (const float*)d_in[0];
    const float* pts = (const float*)d_in[1];
    const int*   fps = (const int*)d_in[2];
    const float* w0  = (const float*)d_in[3];
    const float* b0  = (const float*)d_in[4];
    const float* g0  = (const float*)d_in[5];
    const float* be0 = (const float*)d_in[6];
    const float* w1  = (const float*)d_in[7];
    const float* b1  = (const float*)d_in[8];
    const float* g1  = (const float*)d_in[9];
    const float* be1 = (const float*)d_in[10];
    const float* w2  = (const float*)d_in[11];
    const float* b2  = (const float*)d_in[12];
    const float* g2  = (const float*)d_in[13];
    const float* be2 = (const float*)d_in[14];

    float* ws = (float*)d_ws;
    float* out_xyz = (float*)d_out;
    float* out_pts = (float*)d_out + NG * 3;

    k_prep<<<1, 256, 0, stream>>>(w0, w1, w2, ws);
    k_select<<<NG / 4, 256, 0, stream>>>(xyz, fps, out_xyz, ws);

    if (ws_size >= WS_FAST_BYTES) {
        ushort* h1 = (ushort*)(ws + WS_H1);
        ushort* h2 = (ushort*)(ws + WS_H2);
        k_g1<<<1024, 256, 0, stream>>>(xyz, pts, b0, ws, h1);
        k_fin<<<1, 128, 0, stream>>>(ws + WS_SUMS, g0, be0, ws + WS_SCALE, 0, 64, 0, 64, 64);
        k_g2<<<1024, 256, 0, stream>>>(b1, ws, h1, h2);
        k_fin<<<1, 128, 0, stream>>>(ws + WS_SUMS, g1, be1, ws + WS_SCALE, 128, 192, 128, 192, 64);
        k_g3<<<1024, 256, 0, stream>>>(b2, g2, ws, h2, out_pts);
        k_fin<<<1, 128, 0, stream>>>(ws + WS_SUMS, g2, be2, ws + WS_SCALE, 256, 384, 256, 384, 128);
    } else {
        k_passF<1><<<1024, 256, 0, stream>>>(xyz, pts, b0, b1, b2, g2, ws, out_pts);
        k_fin<<<1, 128, 0, stream>>>(ws + WS_SUMS, g0, be0, ws + WS_SCALE, 0, 64, 0, 64, 64);
        k_passF<2><<<1024, 256, 0, stream>>>(xyz, pts, b0, b1, b2, g2, ws, out_pts);
        k_fin<<<1, 128, 0, stream>>>(ws + WS_SUMS, g1, be1, ws + WS_SCALE, 128, 192, 128, 192, 64);
        k_passF<3><<<1024, 256, 0, stream>>>(xyz, pts, b0, b1, b2, g2, ws, out_pts);
        k_fin<<<1, 128, 0, stream>>>(ws + WS_SUMS, g2, be2, ws + WS_SCALE, 256, 384, 256, 384, 128);
    }
    k_bnmax<<<NG * 128 / 256, 256, 0, stream>>>(out_pts, ws + WS_SCALE);
}

// Round 7
// 390.217 us; speedup vs baseline: 15.0046x; 1.4333x over previous
//
#include <hip/hip_runtime.h>
#include <hip/hip_bf16.h>

// All float tensors are fp32 (reference dtypes, bf16-grid values). fps_idx int32.

typedef __attribute__((ext_vector_type(8))) short short8;
typedef __attribute__((ext_vector_type(4))) float float4v;

constexpr int BB = 16, NN = 4096, SS = 1024, DD = 64, KK = 32;
constexpr int PP = BB * SS * KK;            // 524288 grouped points
constexpr int NG = BB * SS;                 // 16384 query groups
constexpr float EPSF = 1e-5f;
constexpr int CAND_MAX = 640;               // per-wave kNN candidate cap

// Workspace layout (float offsets).
constexpr int WS_IDX   = 0;                    // ushort[PP]
constexpr int WS_NXYZ  = PP / 2;               // float[NG*3]
constexpr int WS_W0PK  = WS_NXYZ + NG*3;       // ushort[6144]  W0' frag image (K=96: feat + xyz hi/lo)
constexpr int WS_W1PK  = WS_W0PK + 3072;       // ushort[4096]  W1' frag image (K=64, bf16-only)
constexpr int WS_W2PK  = WS_W1PK + 2048;       // ushort[8192]  W2' frag image (K=64, bf16-only)
constexpr int WS_W1PKD = WS_W2PK + 4096;       // ushort[8192]  W1 dup image (K=128 hi/lo, fallback)
constexpr int WS_W2PKD = WS_W1PKD + 4096;      // ushort[16384] W2 dup image (K=128 hi/lo, fallback)
constexpr int WS_SUMS  = WS_W2PKD + 8192;      // float[512]
constexpr int WS_SCALE = WS_SUMS + 512;        // float[512]
constexpr int WS_H1    = WS_SCALE + 512;       // ushort[PP*64] pre-BN H1 (bf16)
constexpr int WS_H2    = WS_H1 + PP*32;        // ushort[PP*64] pre-BN H2 (bf16)
constexpr int WS_END   = WS_H2 + PP*32;
constexpr size_t WS_FAST_BYTES = (size_t)WS_END * 4;

__device__ __forceinline__ unsigned rtne16(float x) {
    unsigned b = __float_as_uint(x);
    return (b + 0x7fffu + ((b >> 16) & 1u)) >> 16;
}
// bf16 RTNE bits left in [31:16]
__device__ __forceinline__ unsigned rtneb(float r) {
    unsigned b = __float_as_uint(r);
    return b + 0x7fffu + ((b >> 16) & 1u);
}
// pack: low16 = a[31:16], high16 = b[31:16]
__device__ __forceinline__ unsigned pk2r(unsigned a, unsigned b) {
    return __builtin_amdgcn_perm(a, b, 0x03020706u);
}
__device__ __forceinline__ unsigned pk2f(float a, float b) {
    return pk2r(__float_as_uint(a), __float_as_uint(b));
}
// unpack bf16 pair, apply BN+ReLU per element, repack to bf16 pair
__device__ __forceinline__ unsigned bnpack(unsigned u, float sce, float sfe,
                                           float sco, float sfo) {
    float fe = __uint_as_float(u << 16);
    float fo = __uint_as_float(u & 0xffff0000u);
    float ze = fmaxf(fmaf(fe, sce, sfe), 0.f);
    float zo = fmaxf(fmaf(fo, sco, sfo), 0.f);
    return pk2r(rtneb(ze), rtneb(zo));
}

union UF { uint4 u; short8 s; };
__device__ __forceinline__ short8 ldw(const uint4* __restrict__ p, int idx) {
    UF u; u.u = p[idx]; return u.s;
}

#define LDS_SYNC() asm volatile("s_waitcnt lgkmcnt(0)" ::: "memory")

// ---------------- prep: frag-major bf16 weight images + zero stats ----------------
__global__ void k_prep(const float* __restrict__ w0, const float* __restrict__ w1,
                       const float* __restrict__ w2, float* __restrict__ ws) {
    const int t = threadIdx.x;
    ushort* w0pk = (ushort*)(ws + WS_W0PK);
    for (int i = t; i < 6144; i += 256) {        // [Nt(4)][Ks(3)][lane(64)][j(8)]
        int j = i & 7, l = (i >> 3) & 63, Ks = (i >> 9) % 3, Nt = i / 1536;
        int o = Nt*16 + (l & 15);
        int k = Ks*32 + (l >> 4)*8 + j;
        float v = 0.f;
        if (k < 64)      v = w0[o*67 + 3 + k];
        else if (k < 67) v = w0[o*67 + (k - 64)];     // xyz hi
        else if (k < 70) v = w0[o*67 + (k - 67)];     // xyz lo (same weights)
        w0pk[i] = (ushort)rtne16(v);
    }
    ushort* w1pk = (ushort*)(ws + WS_W1PK);
    for (int i = t; i < 4096; i += 256) {        // [Nt(4)][Ks(2)][lane][j], K=64
        int j = i & 7, l = (i >> 3) & 63, Ks = (i >> 9) & 1, Nt = i >> 10;
        int o = Nt*16 + (l & 15);
        int k = Ks*32 + (l >> 4)*8 + j;
        w1pk[i] = (ushort)rtne16(w1[o*64 + k]);
    }
    ushort* w2pk = (ushort*)(ws + WS_W2PK);
    for (int i = t; i < 8192; i += 256) {        // [Nt(8)][Ks(2)][lane][j], K=64
        int j = i & 7, l = (i >> 3) & 63, Ks = (i >> 9) & 1, Nt = i >> 10;
        int o = Nt*16 + (l & 15);
        int k = Ks*32 + (l >> 4)*8 + j;
        w2pk[i] = (ushort)rtne16(w2[o*64 + k]);
    }
    // fallback dup images (K=128 hi/lo interleaved)
    ushort* w1pd = (ushort*)(ws + WS_W1PKD);
    for (int i = t; i < 8192; i += 256) {        // [Nt(4)][Ks(4)][lane][j]
        int j = i & 7, l = (i >> 3) & 63, Ks = (i >> 9) & 3, Nt = i >> 11;
        int o = Nt*16 + (l & 15);
        int c = (Ks*32 + (l >> 4)*8 + j) >> 1;
        w1pd[i] = (ushort)rtne16(w1[o*64 + c]);
    }
    ushort* w2pd = (ushort*)(ws + WS_W2PKD);
    for (int i = t; i < 16384; i += 256) {       // [Nt(8)][Ks(4)][lane][j]
        int j = i & 7, l = (i >> 3) & 63, Ks = (i >> 9) & 3, Nt = i >> 11;
        int o = Nt*16 + (l & 15);
        int c = (Ks*32 + (l >> 4)*8 + j) >> 1;
        w2pd[i] = (ushort)rtne16(w2[o*64 + c]);
    }
    for (int i = t; i < 512; i += 256) ws[WS_SUMS + i] = 0.f;
}

// ---------------- select: exact top-32 nearest neighbors per query ----------------
// One wave per query. Phase 1: 64 keys/lane in regs, bound B = wave-max of lane
// minima (>= 64th smallest >= T). Phase 2: ballot-scan compaction of keys <= B
// into a per-wave LDS candidate list (ascending global index by construction).
// Phase 3: binary search for T over the compact list (<=10 cand/lane), exact
// top_k tie semantics via ordered strict/tie emission. Overflow (>640 cands,
// P~3e-3/query) falls back to the fully-unrolled in-register path.
__global__ __launch_bounds__(256, 2) void k_select(
    const float* __restrict__ xyz, const int* __restrict__ fps,
    float* __restrict__ out_xyz, float* __restrict__ ws)
{
    __shared__ float sxy[2*NN];                 // 32 KB interleaved x,y
    __shared__ float szz[NN];                   // 16 KB z
    __shared__ unsigned cbk[4][CAND_MAX];       // 10 KB candidate keys
    __shared__ ushort  cbi[4][CAND_MAX];        //  5 KB candidate indices
    const int tid = threadIdx.x;
    const int qb = blockIdx.x * 4;
    const int b  = qb >> 10;
    const float* xb = xyz + (long)b * NN * 3;
    for (int i = tid; i < NN; i += 256) {
        sxy[2*i]   = xb[i*3 + 0];
        sxy[2*i+1] = xb[i*3 + 1];
        szz[i]     = xb[i*3 + 2];
    }
    __syncthreads();

    const int wave = tid >> 6, lane = tid & 63;
    const int q = qb + wave;
    const int nq = fps[q];
    const float qx = sxy[2*nq], qy = sxy[2*nq+1], qz = szz[nq];
    const float qw = __fadd_rn(__fadd_rn(__fmul_rn(qx,qx), __fmul_rn(qy,qy)), __fmul_rn(qz,qz));

    float* nxyz = ws + WS_NXYZ;
    unsigned short* idx_ws = (unsigned short*)ws;
    if (lane < 3) {
        float v = (lane == 0) ? qx : ((lane == 1) ? qy : qz);
        out_xyz[q*3 + lane] = v;
        nxyz[q*3 + lane] = v;
    }

    unsigned key[64];
    unsigned lmin = 0xFFFFFFFFu, lmax = 0u;
    #pragma unroll
    for (int i = 0; i < 64; ++i) {
        const int n = i*64 + lane;
        const float px = sxy[2*n], py = sxy[2*n+1], pz = szz[n];
        const float pw = __fadd_rn(__fadd_rn(__fmul_rn(px,px), __fmul_rn(py,py)), __fmul_rn(pz,pz));
        float dot = fmaf(qx, px, 0.f);
        dot = fmaf(qy, py, dot);
        dot = fmaf(qz, pz, dot);
        float d = __fadd_rn(__fadd_rn(__fmul_rn(-2.0f, dot), qw), pw);
        unsigned u = __float_as_uint(d);
        unsigned k = u ^ (unsigned)(((int)u >> 31) | 0x80000000);
        key[i] = k;
        lmin = min(lmin, k); lmax = max(lmax, k);
    }
    unsigned gmin = lmin, gmax = lmax, Bv = lmin;
    #pragma unroll
    for (int off = 32; off > 0; off >>= 1) {
        gmin = min(gmin, (unsigned)__shfl_xor((int)gmin, off));
        gmax = max(gmax, (unsigned)__shfl_xor((int)gmax, off));
        Bv   = max(Bv,   (unsigned)__shfl_xor((int)Bv,   off));
    }
    // Bv = max of lane minima >= 64th smallest key >= T

    const unsigned long long lmask = (1ull << lane) - 1ull;
    unsigned* ckw = cbk[wave];
    ushort*   ciw = cbi[wave];

    int cnt = 0;
    #pragma unroll
    for (int i = 0; i < 64; ++i) {
        bool pr = key[i] <= Bv;
        unsigned long long m = __ballot(pr);
        int pos = cnt + (int)__popcll(m & lmask);
        if (pr && pos < CAND_MAX) {
            ckw[pos] = key[i];
            ciw[pos] = (ushort)(i*64 + lane);
        }
        cnt += (int)__popcll(m);
    }
    const int base = q * KK;

    if (cnt <= CAND_MAX) {
        LDS_SYNC();
        // candidates into regs (static 10 slots, predicated)
        unsigned cr[10]; ushort ir[10];
        #pragma unroll
        for (int r = 0; r < 10; ++r) {
            int j = r*64 + lane;
            bool v = j < cnt;
            cr[r] = v ? ckw[j] : 0xFFFFFFFFu;
            ir[r] = v ? ciw[j] : (ushort)0;
        }
        // binary search smallest T in [gmin, Bv] with count(<=T) >= 32
        unsigned lo = gmin, hi = Bv;
        while (lo < hi) {
            unsigned mid = lo + ((hi - lo) >> 1);
            int c = 0;
            #pragma unroll
            for (int r = 0; r < 10; ++r)
                c += (int)__popcll(__ballot(cr[r] <= mid));
            if (c >= 32) hi = mid; else lo = mid + 1;
        }
        const unsigned T = lo;

        int c2 = 0;
        #pragma unroll
        for (int r = 0; r < 10; ++r) {           // strictly closer (count < 32)
            bool pr = cr[r] < T;
            unsigned long long m = __ballot(pr);
            if (pr) idx_ws[base + c2 + (int)__popcll(m & lmask)] = ir[r];
            c2 += (int)__popcll(m);
        }
        #pragma unroll
        for (int r = 0; r < 10; ++r) {           // ties, smallest index first
            bool pr = cr[r] == T;
            unsigned long long m = __ballot(pr);
            int pos = c2 + (int)__popcll(m & lmask);
            if (pr && pos < KK) idx_ws[base + pos] = ir[r];
            c2 += (int)__popcll(m);
        }
    } else {
        // rare fallback: full-range in-register search (all loops static-unrolled)
        unsigned lo = gmin, hi = gmax;
        while (lo < hi) {
            unsigned mid = lo + ((hi - lo) >> 1);
            int c = 0;
            #pragma unroll
            for (int i = 0; i < 64; ++i)
                c += (int)__popcll(__ballot(key[i] <= mid));
            if (c >= 32) hi = mid; else lo = mid + 1;
        }
        const unsigned T = lo;
        int c2 = 0;
        #pragma unroll
        for (int i = 0; i < 64; ++i) {
            bool pr = key[i] < T;
            unsigned long long m = __ballot(pr);
            if (pr) idx_ws[base + c2 + (int)__popcll(m & lmask)] = (ushort)(i*64 + lane);
            c2 += (int)__popcll(m);
        }
        #pragma unroll
        for (int i = 0; i < 64; ++i) {
            bool pr = key[i] == T;
            unsigned long long m = __ballot(pr);
            int pos = c2 + (int)__popcll(m & lmask);
            if (pr && pos < KK) idx_ws[base + pos] = (ushort)(i*64 + lane);
            c2 += (int)__popcll(m);
        }
    }
}

// ================= fast path: materialized pre-BN activations =================
// H layout: ushort bf16 H[p][c], p = grouped point (g*32 + m). A-frag reads and
// C-writes are coalesced; no LDS roundtrip, no recompute.

// ---- pass A: gather + GEMM1 -> H1 + stats1 ----
__global__ __launch_bounds__(256, 2) void k_g1(
    const float* __restrict__ xyz, const float* __restrict__ pts,
    const float* __restrict__ b0, float* __restrict__ ws,
    ushort* __restrict__ h1)
{
    __shared__ float rbuf[4][128];
    const int tid = threadIdx.x;
    const int wv = tid >> 6, l = tid & 63, ln = l & 15, q8 = l >> 4;

    const ushort* idxw = (const ushort*)ws;
    const float* nxyz = ws + WS_NXYZ;
    float* sums = ws + WS_SUMS;
    const uint4* w0f = (const uint4*)(ws + WS_W0PK);

    short8 w0r[12];
    #pragma unroll
    for (int t = 0; t < 12; ++t) w0r[t] = ldw(w0f, t*64 + l);
    float b0v[4];
    #pragma unroll
    for (int n = 0; n < 4; ++n) b0v[n] = b0[n*16 + ln];

    float s[4] = {0,0,0,0}, sq[4] = {0,0,0,0};
    const int gbase = blockIdx.x*4 + wv;

    for (int it = 0; it < 4; ++it) {
        const int g = gbase + it*4096;
        const float nqx = nxyz[g*3+0], nqy = nxyz[g*3+1], nqz = nxyz[g*3+2];

        short8 a1[2][3];
        #pragma unroll
        for (int Mt = 0; Mt < 2; ++Mt) {
            int nb = idxw[g*32 + Mt*16 + ln];
            int row = (g >> 10)*NN + nb;
            const float* p = pts + row*64 + q8*8;
            float4 f0 = *(const float4*)p;
            float4 f1 = *(const float4*)(p + 4);
            float4 f2 = *(const float4*)(p + 32);
            float4 f3 = *(const float4*)(p + 36);
            UF t0, t1;
            t0.u.x = pk2f(f0.x, f0.y); t0.u.y = pk2f(f0.z, f0.w);
            t0.u.z = pk2f(f1.x, f1.y); t0.u.w = pk2f(f1.z, f1.w);
            a1[Mt][0] = t0.s;
            t1.u.x = pk2f(f2.x, f2.y); t1.u.y = pk2f(f2.z, f2.w);
            t1.u.z = pk2f(f3.x, f3.y); t1.u.w = pk2f(f3.z, f3.w);
            a1[Mt][1] = t1.s;
            UF x; x.u = make_uint4(0,0,0,0);
            if (q8 == 0) {
                float vx = xyz[row*3+0] - nqx;
                float vy = xyz[row*3+1] - nqy;
                float vz = xyz[row*3+2] - nqz;
                unsigned bx = __float_as_uint(vx), by = __float_as_uint(vy), bz = __float_as_uint(vz);
                float rx = vx - __uint_as_float(bx & 0xffff0000u);
                float ry = vy - __uint_as_float(by & 0xffff0000u);
                float rz = vz - __uint_as_float(bz & 0xffff0000u);
                x.u.x = pk2r(bx, by);
                x.u.y = pk2r(bz, rtneb(rx));
                x.u.z = pk2r(rtneb(ry), rtneb(rz));
            }
            a1[Mt][2] = x.s;
        }

        float4v acc[2][4];
        #pragma unroll
        for (int Mt = 0; Mt < 2; ++Mt)
            #pragma unroll
            for (int Nt = 0; Nt < 4; ++Nt)
                acc[Mt][Nt] = (float4v){b0v[Nt], b0v[Nt], b0v[Nt], b0v[Nt]};
        #pragma unroll
        for (int Ks = 0; Ks < 3; ++Ks)
            #pragma unroll
            for (int Nt = 0; Nt < 4; ++Nt)
                #pragma unroll
                for (int Mt = 0; Mt < 2; ++Mt)
                    acc[Mt][Nt] = __builtin_amdgcn_mfma_f32_16x16x32_bf16(
                        a1[Mt][Ks], w0r[Nt*3 + Ks], acc[Mt][Nt], 0, 0, 0);

        #pragma unroll
        for (int Mt = 0; Mt < 2; ++Mt)
            #pragma unroll
            for (int Nt = 0; Nt < 4; ++Nt)
                #pragma unroll
                for (int r = 0; r < 4; ++r) {
                    float h = acc[Mt][Nt][r];
                    s[Nt] += h; sq[Nt] += h*h;
                    h1[(g*32 + Mt*16 + q8*4 + r)*64 + Nt*16 + ln] = (ushort)rtne16(h);
                }
    }

    #pragma unroll
    for (int t = 0; t < 4; ++t) {
        float a = s[t], b = sq[t];
        a += __shfl_xor(a, 16); a += __shfl_xor(a, 32);
        b += __shfl_xor(b, 16); b += __shfl_xor(b, 32);
        if (l < 16) { rbuf[wv][t*16 + l] = a; rbuf[wv][64 + t*16 + l] = b; }
    }
    __syncthreads();
    if (wv == 0 && l < 16) {
        #pragma unroll
        for (int t = 0; t < 4; ++t) {
            float a = rbuf[0][t*16+l] + rbuf[1][t*16+l] + rbuf[2][t*16+l] + rbuf[3][t*16+l];
            float b = rbuf[0][64+t*16+l] + rbuf[1][64+t*16+l] + rbuf[2][64+t*16+l] + rbuf[3][64+t*16+l];
            atomicAdd(&sums[t*16 + l], a);
            atomicAdd(&sums[64 + t*16 + l], b);
        }
    }
}

// ---- pass B: H1 -> BN1+ReLU -> GEMM2 -> H2 + stats2 ----
__global__ __launch_bounds__(256, 2) void k_g2(
    const float* __restrict__ b1, float* __restrict__ ws,
    const ushort* __restrict__ h1, ushort* __restrict__ h2)
{
    __shared__ float rbuf[4][128];
    const int tid = threadIdx.x;
    const int wv = tid >> 6, l = tid & 63, ln = l & 15, q8 = l >> 4;

    const float* scl = ws + WS_SCALE;
    float* sums = ws + WS_SUMS;
    const uint4* w1f = (const uint4*)(ws + WS_W1PK);

    float b1v[4];
    #pragma unroll
    for (int n = 0; n < 4; ++n) b1v[n] = b1[n*16 + ln];
    float4 sc[2][2], sf[2][2];
    #pragma unroll
    for (int Ks = 0; Ks < 2; ++Ks) {
        sc[Ks][0] = *(const float4*)&scl[Ks*32 + q8*8];
        sc[Ks][1] = *(const float4*)&scl[Ks*32 + q8*8 + 4];
        sf[Ks][0] = *(const float4*)&scl[64 + Ks*32 + q8*8];
        sf[Ks][1] = *(const float4*)&scl[64 + Ks*32 + q8*8 + 4];
    }

    float s[4] = {0,0,0,0}, sq[4] = {0,0,0,0};
    const int gbase = blockIdx.x*4 + wv;

    for (int it = 0; it < 4; ++it) {
        const int g = gbase + it*4096;

        short8 a[2][2];
        #pragma unroll
        for (int Mt = 0; Mt < 2; ++Mt)
            #pragma unroll
            for (int Ks = 0; Ks < 2; ++Ks) {
                uint4 hv = *(const uint4*)&h1[(g*32 + Mt*16 + ln)*64 + Ks*32 + q8*8];
                UF t;
                t.u.x = bnpack(hv.x, sc[Ks][0].x, sf[Ks][0].x, sc[Ks][0].y, sf[Ks][0].y);
                t.u.y = bnpack(hv.y, sc[Ks][0].z, sf[Ks][0].z, sc[Ks][0].w, sf[Ks][0].w);
                t.u.z = bnpack(hv.z, sc[Ks][1].x, sf[Ks][1].x, sc[Ks][1].y, sf[Ks][1].y);
                t.u.w = bnpack(hv.w, sc[Ks][1].z, sf[Ks][1].z, sc[Ks][1].w, sf[Ks][1].w);
                a[Mt][Ks] = t.s;
            }

        float4v acc[2][4];
        #pragma unroll
        for (int Mt = 0; Mt < 2; ++Mt)
            #pragma unroll
            for (int Nt = 0; Nt < 4; ++Nt)
                acc[Mt][Nt] = (float4v){b1v[Nt], b1v[Nt], b1v[Nt], b1v[Nt]};
        #pragma unroll
        for (int Ks = 0; Ks < 2; ++Ks)
            #pragma unroll
            for (int Nt = 0; Nt < 4; ++Nt) {
                short8 bf = ldw(w1f, (Nt*2 + Ks)*64 + l);
                #pragma unroll
                for (int Mt = 0; Mt < 2; ++Mt)
                    acc[Mt][Nt] = __builtin_amdgcn_mfma_f32_16x16x32_bf16(
                        a[Mt][Ks], bf, acc[Mt][Nt], 0, 0, 0);
            }

        #pragma unroll
        for (int Mt = 0; Mt < 2; ++Mt)
            #pragma unroll
            for (int Nt = 0; Nt < 4; ++Nt)
                #pragma unroll
                for (int r = 0; r < 4; ++r) {
                    float h = acc[Mt][Nt][r];
                    s[Nt] += h; sq[Nt] += h*h;
                    h2[(g*32 + Mt*16 + q8*4 + r)*64 + Nt*16 + ln] = (ushort)rtne16(h);
                }
    }

    #pragma unroll
    for (int t = 0; t < 4; ++t) {
        float a = s[t], b = sq[t];
        a += __shfl_xor(a, 16); a += __shfl_xor(a, 32);
        b += __shfl_xor(b, 16); b += __shfl_xor(b, 32);
        if (l < 16) { rbuf[wv][t*16 + l] = a; rbuf[wv][64 + t*16 + l] = b; }
    }
    __syncthreads();
    if (wv == 0 && l < 16) {
        #pragma unroll
        for (int t = 0; t < 4; ++t) {
            float a = rbuf[0][t*16+l] + rbuf[1][t*16+l] + rbuf[2][t*16+l] + rbuf[3][t*16+l];
            float b = rbuf[0][64+t*16+l] + rbuf[1][64+t*16+l] + rbuf[2][64+t*16+l] + rbuf[3][64+t*16+l];
            atomicAdd(&sums[128 + t*16 + l], a);
            atomicAdd(&sums[192 + t*16 + l], b);
        }
    }
}

// ---- pass C: H2 -> BN2+ReLU -> GEMM3 -> stats3 + pre-BN pool -> out ----
__global__ __launch_bounds__(256, 2) void k_g3(
    const float* __restrict__ b2, const float* __restrict__ g2,
    float* __restrict__ ws, const ushort* __restrict__ h2,
    float* __restrict__ out_pts)
{
    __shared__ float rbuf[4][256];
    const int tid = threadIdx.x;
    const int wv = tid >> 6, l = tid & 63, ln = l & 15, q8 = l >> 4;

    const float* scl = ws + WS_SCALE;
    float* sums = ws + WS_SUMS;
    const uint4* w2f = (const uint4*)(ws + WS_W2PK);

    float b2v[8], g2v[8];
    #pragma unroll
    for (int n = 0; n < 8; ++n) { b2v[n] = b2[n*16 + ln]; g2v[n] = g2[n*16 + ln]; }
    float4 sc[2][2], sf[2][2];
    #pragma unroll
    for (int Ks = 0; Ks < 2; ++Ks) {
        sc[Ks][0] = *(const float4*)&scl[128 + Ks*32 + q8*8];
        sc[Ks][1] = *(const float4*)&scl[128 + Ks*32 + q8*8 + 4];
        sf[Ks][0] = *(const float4*)&scl[192 + Ks*32 + q8*8];
        sf[Ks][1] = *(const float4*)&scl[192 + Ks*32 + q8*8 + 4];
    }

    float s[8] = {0,0,0,0,0,0,0,0}, sq[8] = {0,0,0,0,0,0,0,0};
    const int gbase = blockIdx.x*4 + wv;

    for (int it = 0; it < 4; ++it) {
        const int g = gbase + it*4096;

        short8 a[2][2];
        #pragma unroll
        for (int Mt = 0; Mt < 2; ++Mt)
            #pragma unroll
            for (int Ks = 0; Ks < 2; ++Ks) {
                uint4 hv = *(const uint4*)&h2[(g*32 + Mt*16 + ln)*64 + Ks*32 + q8*8];
                UF t;
                t.u.x = bnpack(hv.x, sc[Ks][0].x, sf[Ks][0].x, sc[Ks][0].y, sf[Ks][0].y);
                t.u.y = bnpack(hv.y, sc[Ks][0].z, sf[Ks][0].z, sc[Ks][0].w, sf[Ks][0].w);
                t.u.z = bnpack(hv.z, sc[Ks][1].x, sf[Ks][1].x, sc[Ks][1].y, sf[Ks][1].y);
                t.u.w = bnpack(hv.w, sc[Ks][1].z, sf[Ks][1].z, sc[Ks][1].w, sf[Ks][1].w);
                a[Mt][Ks] = t.s;
            }

        float4v acc[2][8];
        #pragma unroll
        for (int Mt = 0; Mt < 2; ++Mt)
            #pragma unroll
            for (int Nt = 0; Nt < 8; ++Nt)
                acc[Mt][Nt] = (float4v){b2v[Nt], b2v[Nt], b2v[Nt], b2v[Nt]};
        #pragma unroll
        for (int Ks = 0; Ks < 2; ++Ks)
            #pragma unroll
            for (int Nt = 0; Nt < 8; ++Nt) {
                short8 bf = ldw(w2f, (Nt*2 + Ks)*64 + l);
                #pragma unroll
                for (int Mt = 0; Mt < 2; ++Mt)
                    acc[Mt][Nt] = __builtin_amdgcn_mfma_f32_16x16x32_bf16(
                        a[Mt][Ks], bf, acc[Mt][Nt], 0, 0, 0);
            }

        float mm[8];
        #pragma unroll
        for (int Nt = 0; Nt < 8; ++Nt) {
            const bool pos = g2v[Nt] >= 0.f;
            float m = acc[0][Nt][0];
            #pragma unroll
            for (int Mt = 0; Mt < 2; ++Mt)
                #pragma unroll
                for (int r = 0; r < 4; ++r) {
                    float h = acc[Mt][Nt][r];
                    s[Nt] += h; sq[Nt] += h*h;
                    if (!(Mt == 0 && r == 0))
                        m = pos ? fmaxf(m, h) : fminf(m, h);
                }
            float o = __shfl_xor(m, 16); m = pos ? fmaxf(m, o) : fminf(m, o);
            o = __shfl_xor(m, 32);       m = pos ? fmaxf(m, o) : fminf(m, o);
            mm[Nt] = m;
        }
        if (l < 16) {
            #pragma unroll
            for (int Nt = 0; Nt < 8; ++Nt)
                out_pts[(long)g*128 + Nt*16 + l] = mm[Nt];
        }
    }

    #pragma unroll
    for (int t = 0; t < 8; ++t) {
        float a = s[t], b = sq[t];
        a += __shfl_xor(a, 16); a += __shfl_xor(a, 32);
        b += __shfl_xor(b, 16); b += __shfl_xor(b, 32);
        if (l < 16) { rbuf[wv][t*16 + l] = a; rbuf[wv][128 + t*16 + l] = b; }
    }
    __syncthreads();
    if (wv == 0 && l < 16) {
        #pragma unroll
        for (int t = 0; t < 8; ++t) {
            float a = rbuf[0][t*16+l] + rbuf[1][t*16+l] + rbuf[2][t*16+l] + rbuf[3][t*16+l];
            float b = rbuf[0][128+t*16+l] + rbuf[1][128+t*16+l] + rbuf[2][128+t*16+l] + rbuf[3][128+t*16+l];
            atomicAdd(&sums[256 + t*16 + l], a);
            atomicAdd(&sums[384 + t*16 + l], b);
        }
    }
}

// ================= fallback path (small ws): recompute, R4-style =================
template<int STAGE>
__global__ __launch_bounds__(256, 2) void k_passF(
    const float* __restrict__ xyz, const float* __restrict__ pts,
    const float* __restrict__ b0, const float* __restrict__ b1,
    const float* __restrict__ b2, const float* __restrict__ g2,
    float* __restrict__ ws, float* __restrict__ out_pts)
{
    __shared__ __align__(16) ushort zb[(STAGE >= 2) ? 4*32*136 : 8];
    const int tid = threadIdx.x;
    const int wv = tid >> 6, l = tid & 63, ln = l & 15, q8 = l >> 4;
    ushort* zw = &zb[(STAGE >= 2) ? wv*32*136 : 0];

    const ushort* idxw = (const ushort*)ws;
    const float* nxyz = ws + WS_NXYZ;
    const float* scl  = ws + WS_SCALE;
    float*       sums = ws + WS_SUMS;
    const uint4* w0f = (const uint4*)(ws + WS_W0PK);
    const uint4* w1f = (const uint4*)(ws + WS_W1PKD);
    const uint4* w2f = (const uint4*)(ws + WS_W2PKD);

    float b0v[4];
    #pragma unroll
    for (int n = 0; n < 4; ++n) b0v[n] = b0[n*16 + ln];
    float sc1v[4], sf1v[4], b1v[4];
    if constexpr (STAGE >= 2) {
        #pragma unroll
        for (int n = 0; n < 4; ++n) {
            sc1v[n] = scl[n*16 + ln]; sf1v[n] = scl[64 + n*16 + ln];
            b1v[n] = b1[n*16 + ln];
        }
    }
    float sc2v[4], sf2v[4], b2v[8], g2v[8];
    if constexpr (STAGE >= 3) {
        #pragma unroll
        for (int n = 0; n < 4; ++n) {
            sc2v[n] = scl[128 + n*16 + ln]; sf2v[n] = scl[192 + n*16 + ln];
        }
        #pragma unroll
        for (int n = 0; n < 8; ++n) { b2v[n] = b2[n*16 + ln]; g2v[n] = g2[n*16 + ln]; }
    }

    float s[8] = {0,0,0,0,0,0,0,0}, sq[8] = {0,0,0,0,0,0,0,0};

    for (int g = blockIdx.x*4 + wv; g < NG; g += 4096) {
        const float nqx = nxyz[g*3+0], nqy = nxyz[g*3+1], nqz = nxyz[g*3+2];
        short8 a1[2][3];
        #pragma unroll
        for (int Mt = 0; Mt < 2; ++Mt) {
            int nb = idxw[g*32 + Mt*16 + ln];
            int row = (g >> 10)*NN + nb;
            const float* p = pts + row*64 + q8*8;
            float4 f0 = *(const float4*)p, f1 = *(const float4*)(p + 4);
            float4 f2 = *(const float4*)(p + 32), f3 = *(const float4*)(p + 36);
            UF t0, t1;
            t0.u.x = pk2f(f0.x, f0.y); t0.u.y = pk2f(f0.z, f0.w);
            t0.u.z = pk2f(f1.x, f1.y); t0.u.w = pk2f(f1.z, f1.w);
            a1[Mt][0] = t0.s;
            t1.u.x = pk2f(f2.x, f2.y); t1.u.y = pk2f(f2.z, f2.w);
            t1.u.z = pk2f(f3.x, f3.y); t1.u.w = pk2f(f3.z, f3.w);
            a1[Mt][1] = t1.s;
            UF x; x.u = make_uint4(0,0,0,0);
            if (q8 == 0) {
                float vx = xyz[row*3+0] - nqx, vy = xyz[row*3+1] - nqy, vz = xyz[row*3+2] - nqz;
                unsigned bx = __float_as_uint(vx), by = __float_as_uint(vy), bz = __float_as_uint(vz);
                float rx = vx - __uint_as_float(bx & 0xffff0000u);
                float ry = vy - __uint_as_float(by & 0xffff0000u);
                float rz = vz - __uint_as_float(bz & 0xffff0000u);
                x.u.x = pk2r(bx, by);
                x.u.y = pk2r(bz, rtneb(rx));
                x.u.z = pk2r(rtneb(ry), rtneb(rz));
            }
            a1[Mt][2] = x.s;
        }

        float4v acc1[2][4];
        #pragma unroll
        for (int Mt = 0; Mt < 2; ++Mt)
            #pragma unroll
            for (int Nt = 0; Nt < 4; ++Nt)
                acc1[Mt][Nt] = (float4v){b0v[Nt], b0v[Nt], b0v[Nt], b0v[Nt]};
        #pragma unroll
        for (int Ks = 0; Ks < 3; ++Ks)
            #pragma unroll
            for (int Nt = 0; Nt < 4; ++Nt) {
                short8 bf = ldw(w0f, (Nt*3 + Ks)*64 + l);
                #pragma unroll
                for (int Mt = 0; Mt < 2; ++Mt)
                    acc1[Mt][Nt] = __builtin_amdgcn_mfma_f32_16x16x32_bf16(
                        a1[Mt][Ks], bf, acc1[Mt][Nt], 0, 0, 0);
            }

        if constexpr (STAGE == 1) {
            #pragma unroll
            for (int Nt = 0; Nt < 4; ++Nt)
                #pragma unroll
                for (int Mt = 0; Mt < 2; ++Mt)
                    #pragma unroll
                    for (int r = 0; r < 4; ++r) {
                        float h = acc1[Mt][Nt][r];
                        s[Nt] += h; sq[Nt] += h*h;
                    }
        }

        if constexpr (STAGE >= 2) {
            #pragma unroll
            for (int Mt = 0; Mt < 2; ++Mt)
                #pragma unroll
                for (int Nt = 0; Nt < 4; ++Nt)
                    #pragma unroll
                    for (int r = 0; r < 4; ++r) {
                        float z = fmaxf(fmaf(acc1[Mt][Nt][r], sc1v[Nt], sf1v[Nt]), 0.f);
                        unsigned zu = __float_as_uint(z);
                        float rr = z - __uint_as_float(zu & 0xffff0000u);
                        *(unsigned*)&zw[(Mt*16 + q8*4 + r)*136 + 2*(Nt*16 + ln)] = pk2r(zu, rtneb(rr));
                    }
            LDS_SYNC();

            float4v acc2[2][4];
            #pragma unroll
            for (int Mt = 0; Mt < 2; ++Mt)
                #pragma unroll
                for (int Nt = 0; Nt < 4; ++Nt)
                    acc2[Mt][Nt] = (float4v){b1v[Nt], b1v[Nt], b1v[Nt], b1v[Nt]};
            #pragma unroll
            for (int Ks = 0; Ks < 4; ++Ks) {
                short8 a2[2];
                #pragma unroll
                for (int Mt = 0; Mt < 2; ++Mt)
                    a2[Mt] = *(const short8*)&zw[(Mt*16 + ln)*136 + Ks*32 + q8*8];
                #pragma unroll
                for (int Nt = 0; Nt < 4; ++Nt) {
                    short8 bf = ldw(w1f, (Nt*4 + Ks)*64 + l);
                    #pragma unroll
                    for (int Mt = 0; Mt < 2; ++Mt)
                        acc2[Mt][Nt] = __builtin_amdgcn_mfma_f32_16x16x32_bf16(
                            a2[Mt], bf, acc2[Mt][Nt], 0, 0, 0);
                }
            }

            if constexpr (STAGE == 2) {
                #pragma unroll
                for (int Nt = 0; Nt < 4; ++Nt)
                    #pragma unroll
                    for (int Mt = 0; Mt < 2; ++Mt)
                        #pragma unroll
                        for (int r = 0; r < 4; ++r) {
                            float h = acc2[Mt][Nt][r];
                            s[Nt] += h; sq[Nt] += h*h;
                        }
            }

            if constexpr (STAGE == 3) {
                LDS_SYNC();
                #pragma unroll
                for (int Mt = 0; Mt < 2; ++Mt)
                    #pragma unroll
                    for (int Nt = 0; Nt < 4; ++Nt)
                        #pragma unroll
                        for (int r = 0; r < 4; ++r) {
                            float z = fmaxf(fmaf(acc2[Mt][Nt][r], sc2v[Nt], sf2v[Nt]), 0.f);
                            unsigned zu = __float_as_uint(z);
                            float rr = z - __uint_as_float(zu & 0xffff0000u);
                            *(unsigned*)&zw[(Mt*16 + q8*4 + r)*136 + 2*(Nt*16 + ln)] = pk2r(zu, rtneb(rr));
                        }
                LDS_SYNC();

                float4v acc3[2][8];
                #pragma unroll
                for (int Mt = 0; Mt < 2; ++Mt)
                    #pragma unroll
                    for (int Nt = 0; Nt < 8; ++Nt)
                        acc3[Mt][Nt] = (float4v){b2v[Nt], b2v[Nt], b2v[Nt], b2v[Nt]};
                #pragma unroll
                for (int Ks = 0; Ks < 4; ++Ks) {
                    short8 a2[2];
                    #pragma unroll
                    for (int Mt = 0; Mt < 2; ++Mt)
                        a2[Mt] = *(const short8*)&zw[(Mt*16 + ln)*136 + Ks*32 + q8*8];
                    #pragma unroll
                    for (int Nt = 0; Nt < 8; ++Nt) {
                        short8 bf = ldw(w2f, (Nt*4 + Ks)*64 + l);
                        #pragma unroll
                        for (int Mt = 0; Mt < 2; ++Mt)
                            acc3[Mt][Nt] = __builtin_amdgcn_mfma_f32_16x16x32_bf16(
                                a2[Mt], bf, acc3[Mt][Nt], 0, 0, 0);
                    }
                }

                float mm[8];
                #pragma unroll
                for (int Nt = 0; Nt < 8; ++Nt) {
                    const bool pos = g2v[Nt] >= 0.f;
                    float m = acc3[0][Nt][0];
                    #pragma unroll
                    for (int Mt = 0; Mt < 2; ++Mt)
                        #pragma unroll
                        for (int r = 0; r < 4; ++r) {
                            float h = acc3[Mt][Nt][r];
                            s[Nt] += h; sq[Nt] += h*h;
                            if (!(Mt == 0 && r == 0))
                                m = pos ? fmaxf(m, h) : fminf(m, h);
                        }
                    float o = __shfl_xor(m, 16); m = pos ? fmaxf(m, o) : fminf(m, o);
                    o = __shfl_xor(m, 32);       m = pos ? fmaxf(m, o) : fminf(m, o);
                    mm[Nt] = m;
                }
                if (l < 16) {
                    #pragma unroll
                    for (int Nt = 0; Nt < 8; ++Nt)
                        out_pts[(long)g*128 + Nt*16 + l] = mm[Nt];
                }
            }
        }
    }

    constexpr int NT = (STAGE == 3) ? 8 : 4;
    constexpr int soff = (STAGE == 1) ? 0 : (STAGE == 2) ? 128 : 256;
    constexpr int qoff = (STAGE == 1) ? 64 : (STAGE == 2) ? 192 : 384;
    #pragma unroll
    for (int t = 0; t < NT; ++t) {
        float a = s[t], b = sq[t];
        a += __shfl_xor(a, 16); a += __shfl_xor(a, 32);
        b += __shfl_xor(b, 16); b += __shfl_xor(b, 32);
        if (l < 16) {
            atomicAdd(&sums[soff + t*16 + l], a);
            atomicAdd(&sums[qoff + t*16 + l], b);
        }
    }
}

// ---------------- finalize: mean/var -> BN scale/shift ----------------
__global__ void k_fin(const float* __restrict__ sums, const float* __restrict__ g,
                      const float* __restrict__ be, float* __restrict__ scl,
                      int sum_off, int sq_off, int sc_off, int sh_off, int C)
{
    int c = threadIdx.x;
    if (c < C) {
        float mean = sums[sum_off + c] * (1.0f / PP);
        float var  = sums[sq_off + c] * (1.0f / PP) - mean * mean;
        float s = g[c] * rsqrtf(var + EPSF);
        scl[sc_off + c] = s;
        scl[sh_off + c] = be[c] - mean * s;
    }
}

// ---------------- apply BN3+ReLU to the pooled pre-activations ----------------
__global__ void k_bnmax(float* __restrict__ op, const float* __restrict__ scl) {
    int i = blockIdx.x * 256 + threadIdx.x;
    int c = i & 127;
    float sc = scl[256 + c], sf = scl[384 + c];
    op[i] = fmaxf(fmaf(op[i], sc, sf), 0.f);
}

extern "C" void kernel_launch(void* const* d_in, const int* in_sizes, int n_in,
                              void* d_out, int out_size, void* d_ws, size_t ws_size,
                              hipStream_t stream) {
    const float* xyz = (const float*)d_in[0];
    const float* pts = (const float*)d_in[1];
    const int*   fps = (const int*)d_in[2];
    const float* w0  = (const float*)d_in[3];
    const float* b0  = (const float*)d_in[4];
    const float* g0  = (const float*)d_in[5];
    const float* be0 = (const float*)d_in[6];
    const float* w1  = (const float*)d_in[7];
    const float* b1  = (const float*)d_in[8];
    const float* g1  = (const float*)d_in[9];
    const float* be1 = (const float*)d_in[10];
    const float* w2  = (const float*)d_in[11];
    const float* b2  = (const float*)d_in[12];
    const float* g2  = (const float*)d_in[13];
    const float* be2 = (const float*)d_in[14];

    float* ws = (float*)d_ws;
    float* out_xyz = (float*)d_out;
    float* out_pts = (float*)d_out + NG * 3;

    k_prep<<<1, 256, 0, stream>>>(w0, w1, w2, ws);
    k_select<<<NG / 4, 256, 0, stream>>>(xyz, fps, out_xyz, ws);

    if (ws_size >= WS_FAST_BYTES) {
        ushort* h1 = (ushort*)(ws + WS_H1);
        ushort* h2 = (ushort*)(ws + WS_H2);
        k_g1<<<1024, 256, 0, stream>>>(xyz, pts, b0, ws, h1);
        k_fin<<<1, 128, 0, stream>>>(ws + WS_SUMS, g0, be0, ws + WS_SCALE, 0, 64, 0, 64, 64);
        k_g2<<<1024, 256, 0, stream>>>(b1, ws, h1, h2);
        k_fin<<<1, 128, 0, stream>>>(ws + WS_SUMS, g1, be1, ws + WS_SCALE, 128, 192, 128, 192, 64);
        k_g3<<<1024, 256, 0, stream>>>(b2, g2, ws, h2, out_pts);
        k_fin<<<1, 128, 0, stream>>>(ws + WS_SUMS, g2, be2, ws + WS_SCALE, 256, 384, 256, 384, 128);
    } else {
        k_passF<1><<<1024, 256, 0, stream>>>(xyz, pts, b0, b1, b2, g2, ws, out_pts);
        k_fin<<<1, 128, 0, stream>>>(ws + WS_SUMS, g0, be0, ws + WS_SCALE, 0, 64, 0, 64, 64);
        k_passF<2><<<1024, 256, 0, stream>>>(xyz, pts, b0, b1, b2, g2, ws, out_pts);
        k_fin<<<1, 128, 0, stream>>>(ws + WS_SUMS, g1, be1, ws + WS_SCALE, 128, 192, 128, 192, 64);
        k_passF<3><<<1024, 256, 0, stream>>>(xyz, pts, b0, b1, b2, g2, ws, out_pts);
        k_fin<<<1, 128, 0, stream>>>(ws + WS_SUMS, g2, be2, ws + WS_SCALE, 256, 384, 256, 384, 128);
    }
    k_bnmax<<<NG * 128 / 256, 256, 0, stream>>>(out_pts, ws + WS_SCALE);
}

// Round 8
// 387.427 us; speedup vs baseline: 15.1127x; 1.0072x over previous
//
#include <hip/hip_runtime.h>
#include <hip/hip_bf16.h>

// All float tensors are fp32 (reference dtypes, bf16-grid values). fps_idx int32.

typedef __attribute__((ext_vector_type(8))) short short8;
typedef __attribute__((ext_vector_type(4))) float float4v;

constexpr int BB = 16, NN = 4096, SS = 1024, DD = 64, KK = 32;
constexpr int PP = BB * SS * KK;            // 524288 grouped points
constexpr int NG = BB * SS;                 // 16384 query groups
constexpr float EPSF = 1e-5f;
constexpr int CAND_MAX = 640;               // per-wave kNN candidate cap
constexpr int QPB = 8;                      // queries (waves) per select block

// Workspace layout (float offsets).
constexpr int WS_IDX   = 0;                    // ushort[PP]
constexpr int WS_NXYZ  = PP / 2;               // float[NG*3]
constexpr int WS_W0PK  = WS_NXYZ + NG*3;       // ushort[6144]  W0' frag image (K=96: feat + xyz hi/lo)
constexpr int WS_W1PK  = WS_W0PK + 3072;       // ushort[4096]  W1' frag image (K=64, bf16-only)
constexpr int WS_W2PK  = WS_W1PK + 2048;       // ushort[8192]  W2' frag image (K=64, bf16-only)
constexpr int WS_W1PKD = WS_W2PK + 4096;       // ushort[8192]  W1 dup image (K=128 hi/lo, fallback)
constexpr int WS_W2PKD = WS_W1PKD + 4096;      // ushort[16384] W2 dup image (K=128 hi/lo, fallback)
constexpr int WS_SUMS  = WS_W2PKD + 8192;      // float[512]
constexpr int WS_SCALE = WS_SUMS + 512;        // float[512]
constexpr int WS_H1    = WS_SCALE + 512;       // ushort[PP*64] pre-BN H1 (bf16)
constexpr int WS_H2    = WS_H1 + PP*32;        // ushort[PP*64] pre-BN H2 (bf16)
constexpr int WS_END   = WS_H2 + PP*32;
constexpr size_t WS_FAST_BYTES = (size_t)WS_END * 4;

__device__ __forceinline__ unsigned rtne16(float x) {
    unsigned b = __float_as_uint(x);
    return (b + 0x7fffu + ((b >> 16) & 1u)) >> 16;
}
// bf16 RTNE bits left in [31:16]
__device__ __forceinline__ unsigned rtneb(float r) {
    unsigned b = __float_as_uint(r);
    return b + 0x7fffu + ((b >> 16) & 1u);
}
// pack: low16 = a[31:16], high16 = b[31:16]
__device__ __forceinline__ unsigned pk2r(unsigned a, unsigned b) {
    return __builtin_amdgcn_perm(a, b, 0x03020706u);
}
__device__ __forceinline__ unsigned pk2f(float a, float b) {
    return pk2r(__float_as_uint(a), __float_as_uint(b));
}
// unpack bf16 pair, apply BN+ReLU per element, repack to bf16 pair
__device__ __forceinline__ unsigned bnpack(unsigned u, float sce, float sfe,
                                           float sco, float sfo) {
    float fe = __uint_as_float(u << 16);
    float fo = __uint_as_float(u & 0xffff0000u);
    float ze = fmaxf(fmaf(fe, sce, sfe), 0.f);
    float zo = fmaxf(fmaf(fo, sco, sfo), 0.f);
    return pk2r(rtneb(ze), rtneb(zo));
}

union UF { uint4 u; short8 s; };
__device__ __forceinline__ short8 ldw(const uint4* __restrict__ p, int idx) {
    UF u; u.u = p[idx]; return u.s;
}

#define LDS_SYNC() asm volatile("s_waitcnt lgkmcnt(0)" ::: "memory")

// ---------------- prep: frag-major bf16 weight images + zero stats ----------------
__global__ void k_prep(const float* __restrict__ w0, const float* __restrict__ w1,
                       const float* __restrict__ w2, float* __restrict__ ws) {
    const int t = threadIdx.x;
    ushort* w0pk = (ushort*)(ws + WS_W0PK);
    for (int i = t; i < 6144; i += 256) {        // [Nt(4)][Ks(3)][lane(64)][j(8)]
        int j = i & 7, l = (i >> 3) & 63, Ks = (i >> 9) % 3, Nt = i / 1536;
        int o = Nt*16 + (l & 15);
        int k = Ks*32 + (l >> 4)*8 + j;
        float v = 0.f;
        if (k < 64)      v = w0[o*67 + 3 + k];
        else if (k < 67) v = w0[o*67 + (k - 64)];     // xyz hi
        else if (k < 70) v = w0[o*67 + (k - 67)];     // xyz lo (same weights)
        w0pk[i] = (ushort)rtne16(v);
    }
    ushort* w1pk = (ushort*)(ws + WS_W1PK);
    for (int i = t; i < 4096; i += 256) {        // [Nt(4)][Ks(2)][lane][j], K=64
        int j = i & 7, l = (i >> 3) & 63, Ks = (i >> 9) & 1, Nt = i >> 10;
        int o = Nt*16 + (l & 15);
        int k = Ks*32 + (l >> 4)*8 + j;
        w1pk[i] = (ushort)rtne16(w1[o*64 + k]);
    }
    ushort* w2pk = (ushort*)(ws + WS_W2PK);
    for (int i = t; i < 8192; i += 256) {        // [Nt(8)][Ks(2)][lane][j], K=64
        int j = i & 7, l = (i >> 3) & 63, Ks = (i >> 9) & 1, Nt = i >> 10;
        int o = Nt*16 + (l & 15);
        int k = Ks*32 + (l >> 4)*8 + j;
        w2pk[i] = (ushort)rtne16(w2[o*64 + k]);
    }
    // fallback dup images (K=128 hi/lo interleaved)
    ushort* w1pd = (ushort*)(ws + WS_W1PKD);
    for (int i = t; i < 8192; i += 256) {        // [Nt(4)][Ks(4)][lane][j]
        int j = i & 7, l = (i >> 3) & 63, Ks = (i >> 9) & 3, Nt = i >> 11;
        int o = Nt*16 + (l & 15);
        int c = (Ks*32 + (l >> 4)*8 + j) >> 1;
        w1pd[i] = (ushort)rtne16(w1[o*64 + c]);
    }
    ushort* w2pd = (ushort*)(ws + WS_W2PKD);
    for (int i = t; i < 16384; i += 256) {       // [Nt(8)][Ks(4)][lane][j]
        int j = i & 7, l = (i >> 3) & 63, Ks = (i >> 9) & 3, Nt = i >> 11;
        int o = Nt*16 + (l & 15);
        int c = (Ks*32 + (l >> 4)*8 + j) >> 1;
        w2pd[i] = (ushort)rtne16(w2[o*64 + c]);
    }
    for (int i = t; i < 512; i += 256) ws[WS_SUMS + i] = 0.f;
}

// ---------------- select: exact top-32 nearest neighbors per query ----------------
// 8 waves per block share the 48 KB coordinate tile (16 waves/CU occupancy).
// Per wave: 64 keys/lane in regs; bound B = wave-max of lane minima; ballot-scan
// compaction of keys <= B into per-wave LDS list (ascending global index); binary
// search for T over <=10 cand/lane; exact top_k tie semantics via ordered
// strict/tie emission. Overflow (>640 cands) falls back to in-register path.
__global__ __launch_bounds__(512, 2) void k_select(
    const float* __restrict__ xyz, const int* __restrict__ fps,
    float* __restrict__ out_xyz, float* __restrict__ ws)
{
    __shared__ float sxy[2*NN];                 // 32 KB interleaved x,y
    __shared__ float szz[NN];                   // 16 KB z
    __shared__ unsigned cbk[QPB][CAND_MAX];     // 20 KB candidate keys
    __shared__ ushort  cbi[QPB][CAND_MAX];      // 10 KB candidate indices
    const int tid = threadIdx.x;
    const int qb = blockIdx.x * QPB;
    const int b  = qb >> 10;
    const float* xb = xyz + (long)b * NN * 3;
    for (int i = tid; i < NN; i += 512) {
        sxy[2*i]   = xb[i*3 + 0];
        sxy[2*i+1] = xb[i*3 + 1];
        szz[i]     = xb[i*3 + 2];
    }
    __syncthreads();

    const int wave = tid >> 6, lane = tid & 63;
    const int q = qb + wave;
    const int nq = fps[q];
    const float qx = sxy[2*nq], qy = sxy[2*nq+1], qz = szz[nq];
    const float qw = __fadd_rn(__fadd_rn(__fmul_rn(qx,qx), __fmul_rn(qy,qy)), __fmul_rn(qz,qz));

    float* nxyz = ws + WS_NXYZ;
    unsigned short* idx_ws = (unsigned short*)ws;
    if (lane < 3) {
        float v = (lane == 0) ? qx : ((lane == 1) ? qy : qz);
        out_xyz[q*3 + lane] = v;
        nxyz[q*3 + lane] = v;
    }

    unsigned key[64];
    unsigned lmin = 0xFFFFFFFFu, lmax = 0u;
    #pragma unroll
    for (int i = 0; i < 64; ++i) {
        const int n = i*64 + lane;
        const float px = sxy[2*n], py = sxy[2*n+1], pz = szz[n];
        const float pw = __fadd_rn(__fadd_rn(__fmul_rn(px,px), __fmul_rn(py,py)), __fmul_rn(pz,pz));
        float dot = fmaf(qx, px, 0.f);
        dot = fmaf(qy, py, dot);
        dot = fmaf(qz, pz, dot);
        float d = __fadd_rn(__fadd_rn(__fmul_rn(-2.0f, dot), qw), pw);
        unsigned u = __float_as_uint(d);
        unsigned k = u ^ (unsigned)(((int)u >> 31) | 0x80000000);
        key[i] = k;
        lmin = min(lmin, k); lmax = max(lmax, k);
    }
    unsigned gmin = lmin, gmax = lmax, Bv = lmin;
    #pragma unroll
    for (int off = 32; off > 0; off >>= 1) {
        gmin = min(gmin, (unsigned)__shfl_xor((int)gmin, off));
        gmax = max(gmax, (unsigned)__shfl_xor((int)gmax, off));
        Bv   = max(Bv,   (unsigned)__shfl_xor((int)Bv,   off));
    }
    // Bv = max of lane minima >= 64th smallest key >= T

    const unsigned long long lmask = (1ull << lane) - 1ull;
    unsigned* ckw = cbk[wave];
    ushort*   ciw = cbi[wave];

    int cnt = 0;
    #pragma unroll
    for (int i = 0; i < 64; ++i) {
        bool pr = key[i] <= Bv;
        unsigned long long m = __ballot(pr);
        int pos = cnt + (int)__popcll(m & lmask);
        if (pr && pos < CAND_MAX) {
            ckw[pos] = key[i];
            ciw[pos] = (ushort)(i*64 + lane);
        }
        cnt += (int)__popcll(m);
    }
    const int base = q * KK;

    if (cnt <= CAND_MAX) {
        LDS_SYNC();
        // candidates into regs (static 10 slots, predicated)
        unsigned cr[10]; ushort ir[10];
        #pragma unroll
        for (int r = 0; r < 10; ++r) {
            int j = r*64 + lane;
            bool v = j < cnt;
            cr[r] = v ? ckw[j] : 0xFFFFFFFFu;
            ir[r] = v ? ciw[j] : (ushort)0;
        }
        // binary search smallest T in [gmin, Bv] with count(<=T) >= 32
        unsigned lo = gmin, hi = Bv;
        while (lo < hi) {
            unsigned mid = lo + ((hi - lo) >> 1);
            int c = 0;
            #pragma unroll
            for (int r = 0; r < 10; ++r)
                c += (int)__popcll(__ballot(cr[r] <= mid));
            if (c >= 32) hi = mid; else lo = mid + 1;
        }
        const unsigned T = lo;

        int c2 = 0;
        #pragma unroll
        for (int r = 0; r < 10; ++r) {           // strictly closer (count < 32)
            bool pr = cr[r] < T;
            unsigned long long m = __ballot(pr);
            if (pr) idx_ws[base + c2 + (int)__popcll(m & lmask)] = ir[r];
            c2 += (int)__popcll(m);
        }
        #pragma unroll
        for (int r = 0; r < 10; ++r) {           // ties, smallest index first
            bool pr = cr[r] == T;
            unsigned long long m = __ballot(pr);
            int pos = c2 + (int)__popcll(m & lmask);
            if (pr && pos < KK) idx_ws[base + pos] = ir[r];
            c2 += (int)__popcll(m);
        }
    } else {
        // rare fallback: full-range in-register search (all loops static-unrolled)
        unsigned lo = gmin, hi = gmax;
        while (lo < hi) {
            unsigned mid = lo + ((hi - lo) >> 1);
            int c = 0;
            #pragma unroll
            for (int i = 0; i < 64; ++i)
                c += (int)__popcll(__ballot(key[i] <= mid));
            if (c >= 32) hi = mid; else lo = mid + 1;
        }
        const unsigned T = lo;
        int c2 = 0;
        #pragma unroll
        for (int i = 0; i < 64; ++i) {
            bool pr = key[i] < T;
            unsigned long long m = __ballot(pr);
            if (pr) idx_ws[base + c2 + (int)__popcll(m & lmask)] = (ushort)(i*64 + lane);
            c2 += (int)__popcll(m);
        }
        #pragma unroll
        for (int i = 0; i < 64; ++i) {
            bool pr = key[i] == T;
            unsigned long long m = __ballot(pr);
            int pos = c2 + (int)__popcll(m & lmask);
            if (pr && pos < KK) idx_ws[base + pos] = (ushort)(i*64 + lane);
            c2 += (int)__popcll(m);
        }
    }
}

// ================= fast path: materialized pre-BN activations =================
// H layout: ushort bf16 H[p][c], p = grouped point (g*32 + m). A-frag reads and
// C-writes are coalesced; no LDS roundtrip, no recompute.

// ---- pass A: gather + GEMM1 -> H1 + stats1 ----
__global__ __launch_bounds__(256, 2) void k_g1(
    const float* __restrict__ xyz, const float* __restrict__ pts,
    const float* __restrict__ b0, float* __restrict__ ws,
    ushort* __restrict__ h1)
{
    __shared__ float rbuf[4][128];
    const int tid = threadIdx.x;
    const int wv = tid >> 6, l = tid & 63, ln = l & 15, q8 = l >> 4;

    const ushort* idxw = (const ushort*)ws;
    const float* nxyz = ws + WS_NXYZ;
    float* sums = ws + WS_SUMS;
    const uint4* w0f = (const uint4*)(ws + WS_W0PK);

    short8 w0r[12];
    #pragma unroll
    for (int t = 0; t < 12; ++t) w0r[t] = ldw(w0f, t*64 + l);
    float b0v[4];
    #pragma unroll
    for (int n = 0; n < 4; ++n) b0v[n] = b0[n*16 + ln];

    float s[4] = {0,0,0,0}, sq[4] = {0,0,0,0};
    const int gbase = blockIdx.x*4 + wv;

    for (int it = 0; it < 4; ++it) {
        const int g = gbase + it*4096;
        const float nqx = nxyz[g*3+0], nqy = nxyz[g*3+1], nqz = nxyz[g*3+2];

        short8 a1[2][3];
        #pragma unroll
        for (int Mt = 0; Mt < 2; ++Mt) {
            int nb = idxw[g*32 + Mt*16 + ln];
            int row = (g >> 10)*NN + nb;
            const float* p = pts + row*64 + q8*8;
            float4 f0 = *(const float4*)p;
            float4 f1 = *(const float4*)(p + 4);
            float4 f2 = *(const float4*)(p + 32);
            float4 f3 = *(const float4*)(p + 36);
            UF t0, t1;
            t0.u.x = pk2f(f0.x, f0.y); t0.u.y = pk2f(f0.z, f0.w);
            t0.u.z = pk2f(f1.x, f1.y); t0.u.w = pk2f(f1.z, f1.w);
            a1[Mt][0] = t0.s;
            t1.u.x = pk2f(f2.x, f2.y); t1.u.y = pk2f(f2.z, f2.w);
            t1.u.z = pk2f(f3.x, f3.y); t1.u.w = pk2f(f3.z, f3.w);
            a1[Mt][1] = t1.s;
            UF x; x.u = make_uint4(0,0,0,0);
            if (q8 == 0) {
                float vx = xyz[row*3+0] - nqx;
                float vy = xyz[row*3+1] - nqy;
                float vz = xyz[row*3+2] - nqz;
                unsigned bx = __float_as_uint(vx), by = __float_as_uint(vy), bz = __float_as_uint(vz);
                float rx = vx - __uint_as_float(bx & 0xffff0000u);
                float ry = vy - __uint_as_float(by & 0xffff0000u);
                float rz = vz - __uint_as_float(bz & 0xffff0000u);
                x.u.x = pk2r(bx, by);
                x.u.y = pk2r(bz, rtneb(rx));
                x.u.z = pk2r(rtneb(ry), rtneb(rz));
            }
            a1[Mt][2] = x.s;
        }

        float4v acc[2][4];
        #pragma unroll
        for (int Mt = 0; Mt < 2; ++Mt)
            #pragma unroll
            for (int Nt = 0; Nt < 4; ++Nt)
                acc[Mt][Nt] = (float4v){b0v[Nt], b0v[Nt], b0v[Nt], b0v[Nt]};
        #pragma unroll
        for (int Ks = 0; Ks < 3; ++Ks)
            #pragma unroll
            for (int Nt = 0; Nt < 4; ++Nt)
                #pragma unroll
                for (int Mt = 0; Mt < 2; ++Mt)
                    acc[Mt][Nt] = __builtin_amdgcn_mfma_f32_16x16x32_bf16(
                        a1[Mt][Ks], w0r[Nt*3 + Ks], acc[Mt][Nt], 0, 0, 0);

        #pragma unroll
        for (int Mt = 0; Mt < 2; ++Mt)
            #pragma unroll
            for (int Nt = 0; Nt < 4; ++Nt)
                #pragma unroll
                for (int r = 0; r < 4; ++r) {
                    float h = acc[Mt][Nt][r];
                    s[Nt] += h; sq[Nt] += h*h;
                    h1[(g*32 + Mt*16 + q8*4 + r)*64 + Nt*16 + ln] = (ushort)rtne16(h);
                }
    }

    #pragma unroll
    for (int t = 0; t < 4; ++t) {
        float a = s[t], b = sq[t];
        a += __shfl_xor(a, 16); a += __shfl_xor(a, 32);
        b += __shfl_xor(b, 16); b += __shfl_xor(b, 32);
        if (l < 16) { rbuf[wv][t*16 + l] = a; rbuf[wv][64 + t*16 + l] = b; }
    }
    __syncthreads();
    if (wv == 0 && l < 16) {
        #pragma unroll
        for (int t = 0; t < 4; ++t) {
            float a = rbuf[0][t*16+l] + rbuf[1][t*16+l] + rbuf[2][t*16+l] + rbuf[3][t*16+l];
            float b = rbuf[0][64+t*16+l] + rbuf[1][64+t*16+l] + rbuf[2][64+t*16+l] + rbuf[3][64+t*16+l];
            atomicAdd(&sums[t*16 + l], a);
            atomicAdd(&sums[64 + t*16 + l], b);
        }
    }
}

// ---- pass B: H1 -> BN1+ReLU -> GEMM2 -> H2 + stats2 ----
__global__ __launch_bounds__(256, 2) void k_g2(
    const float* __restrict__ b1, float* __restrict__ ws,
    const ushort* __restrict__ h1, ushort* __restrict__ h2)
{
    __shared__ float rbuf[4][128];
    const int tid = threadIdx.x;
    const int wv = tid >> 6, l = tid & 63, ln = l & 15, q8 = l >> 4;

    const float* scl = ws + WS_SCALE;
    float* sums = ws + WS_SUMS;
    const uint4* w1f = (const uint4*)(ws + WS_W1PK);

    float b1v[4];
    #pragma unroll
    for (int n = 0; n < 4; ++n) b1v[n] = b1[n*16 + ln];
    float4 sc[2][2], sf[2][2];
    #pragma unroll
    for (int Ks = 0; Ks < 2; ++Ks) {
        sc[Ks][0] = *(const float4*)&scl[Ks*32 + q8*8];
        sc[Ks][1] = *(const float4*)&scl[Ks*32 + q8*8 + 4];
        sf[Ks][0] = *(const float4*)&scl[64 + Ks*32 + q8*8];
        sf[Ks][1] = *(const float4*)&scl[64 + Ks*32 + q8*8 + 4];
    }

    float s[4] = {0,0,0,0}, sq[4] = {0,0,0,0};
    const int gbase = blockIdx.x*4 + wv;

    for (int it = 0; it < 4; ++it) {
        const int g = gbase + it*4096;

        short8 a[2][2];
        #pragma unroll
        for (int Mt = 0; Mt < 2; ++Mt)
            #pragma unroll
            for (int Ks = 0; Ks < 2; ++Ks) {
                uint4 hv = *(const uint4*)&h1[(g*32 + Mt*16 + ln)*64 + Ks*32 + q8*8];
                UF t;
                t.u.x = bnpack(hv.x, sc[Ks][0].x, sf[Ks][0].x, sc[Ks][0].y, sf[Ks][0].y);
                t.u.y = bnpack(hv.y, sc[Ks][0].z, sf[Ks][0].z, sc[Ks][0].w, sf[Ks][0].w);
                t.u.z = bnpack(hv.z, sc[Ks][1].x, sf[Ks][1].x, sc[Ks][1].y, sf[Ks][1].y);
                t.u.w = bnpack(hv.w, sc[Ks][1].z, sf[Ks][1].z, sc[Ks][1].w, sf[Ks][1].w);
                a[Mt][Ks] = t.s;
            }

        float4v acc[2][4];
        #pragma unroll
        for (int Mt = 0; Mt < 2; ++Mt)
            #pragma unroll
            for (int Nt = 0; Nt < 4; ++Nt)
                acc[Mt][Nt] = (float4v){b1v[Nt], b1v[Nt], b1v[Nt], b1v[Nt]};
        #pragma unroll
        for (int Ks = 0; Ks < 2; ++Ks)
            #pragma unroll
            for (int Nt = 0; Nt < 4; ++Nt) {
                short8 bf = ldw(w1f, (Nt*2 + Ks)*64 + l);
                #pragma unroll
                for (int Mt = 0; Mt < 2; ++Mt)
                    acc[Mt][Nt] = __builtin_amdgcn_mfma_f32_16x16x32_bf16(
                        a[Mt][Ks], bf, acc[Mt][Nt], 0, 0, 0);
            }

        #pragma unroll
        for (int Mt = 0; Mt < 2; ++Mt)
            #pragma unroll
            for (int Nt = 0; Nt < 4; ++Nt)
                #pragma unroll
                for (int r = 0; r < 4; ++r) {
                    float h = acc[Mt][Nt][r];
                    s[Nt] += h; sq[Nt] += h*h;
                    h2[(g*32 + Mt*16 + q8*4 + r)*64 + Nt*16 + ln] = (ushort)rtne16(h);
                }
    }

    #pragma unroll
    for (int t = 0; t < 4; ++t) {
        float a = s[t], b = sq[t];
        a += __shfl_xor(a, 16); a += __shfl_xor(a, 32);
        b += __shfl_xor(b, 16); b += __shfl_xor(b, 32);
        if (l < 16) { rbuf[wv][t*16 + l] = a; rbuf[wv][64 + t*16 + l] = b; }
    }
    __syncthreads();
    if (wv == 0 && l < 16) {
        #pragma unroll
        for (int t = 0; t < 4; ++t) {
            float a = rbuf[0][t*16+l] + rbuf[1][t*16+l] + rbuf[2][t*16+l] + rbuf[3][t*16+l];
            float b = rbuf[0][64+t*16+l] + rbuf[1][64+t*16+l] + rbuf[2][64+t*16+l] + rbuf[3][64+t*16+l];
            atomicAdd(&sums[128 + t*16 + l], a);
            atomicAdd(&sums[192 + t*16 + l], b);
        }
    }
}

// ---- pass C: H2 -> BN2+ReLU -> GEMM3 -> stats3 + pre-BN pool -> out ----
__global__ __launch_bounds__(256, 2) void k_g3(
    const float* __restrict__ b2, const float* __restrict__ g2,
    float* __restrict__ ws, const ushort* __restrict__ h2,
    float* __restrict__ out_pts)
{
    __shared__ float rbuf[4][256];
    const int tid = threadIdx.x;
    const int wv = tid >> 6, l = tid & 63, ln = l & 15, q8 = l >> 4;

    const float* scl = ws + WS_SCALE;
    float* sums = ws + WS_SUMS;
    const uint4* w2f = (const uint4*)(ws + WS_W2PK);

    float b2v[8], g2v[8];
    #pragma unroll
    for (int n = 0; n < 8; ++n) { b2v[n] = b2[n*16 + ln]; g2v[n] = g2[n*16 + ln]; }
    float4 sc[2][2], sf[2][2];
    #pragma unroll
    for (int Ks = 0; Ks < 2; ++Ks) {
        sc[Ks][0] = *(const float4*)&scl[128 + Ks*32 + q8*8];
        sc[Ks][1] = *(const float4*)&scl[128 + Ks*32 + q8*8 + 4];
        sf[Ks][0] = *(const float4*)&scl[192 + Ks*32 + q8*8];
        sf[Ks][1] = *(const float4*)&scl[192 + Ks*32 + q8*8 + 4];
    }

    float s[8] = {0,0,0,0,0,0,0,0}, sq[8] = {0,0,0,0,0,0,0,0};
    const int gbase = blockIdx.x*4 + wv;

    for (int it = 0; it < 4; ++it) {
        const int g = gbase + it*4096;

        short8 a[2][2];
        #pragma unroll
        for (int Mt = 0; Mt < 2; ++Mt)
            #pragma unroll
            for (int Ks = 0; Ks < 2; ++Ks) {
                uint4 hv = *(const uint4*)&h2[(g*32 + Mt*16 + ln)*64 + Ks*32 + q8*8];
                UF t;
                t.u.x = bnpack(hv.x, sc[Ks][0].x, sf[Ks][0].x, sc[Ks][0].y, sf[Ks][0].y);
                t.u.y = bnpack(hv.y, sc[Ks][0].z, sf[Ks][0].z, sc[Ks][0].w, sf[Ks][0].w);
                t.u.z = bnpack(hv.z, sc[Ks][1].x, sf[Ks][1].x, sc[Ks][1].y, sf[Ks][1].y);
                t.u.w = bnpack(hv.w, sc[Ks][1].z, sf[Ks][1].z, sc[Ks][1].w, sf[Ks][1].w);
                a[Mt][Ks] = t.s;
            }

        float4v acc[2][8];
        #pragma unroll
        for (int Mt = 0; Mt < 2; ++Mt)
            #pragma unroll
            for (int Nt = 0; Nt < 8; ++Nt)
                acc[Mt][Nt] = (float4v){b2v[Nt], b2v[Nt], b2v[Nt], b2v[Nt]};
        #pragma unroll
        for (int Ks = 0; Ks < 2; ++Ks)
            #pragma unroll
            for (int Nt = 0; Nt < 8; ++Nt) {
                short8 bf = ldw(w2f, (Nt*2 + Ks)*64 + l);
                #pragma unroll
                for (int Mt = 0; Mt < 2; ++Mt)
                    acc[Mt][Nt] = __builtin_amdgcn_mfma_f32_16x16x32_bf16(
                        a[Mt][Ks], bf, acc[Mt][Nt], 0, 0, 0);
            }

        float mm[8];
        #pragma unroll
        for (int Nt = 0; Nt < 8; ++Nt) {
            const bool pos = g2v[Nt] >= 0.f;
            float m = acc[0][Nt][0];
            #pragma unroll
            for (int Mt = 0; Mt < 2; ++Mt)
                #pragma unroll
                for (int r = 0; r < 4; ++r) {
                    float h = acc[Mt][Nt][r];
                    s[Nt] += h; sq[Nt] += h*h;
                    if (!(Mt == 0 && r == 0))
                        m = pos ? fmaxf(m, h) : fminf(m, h);
                }
            float o = __shfl_xor(m, 16); m = pos ? fmaxf(m, o) : fminf(m, o);
            o = __shfl_xor(m, 32);       m = pos ? fmaxf(m, o) : fminf(m, o);
            mm[Nt] = m;
        }
        if (l < 16) {
            #pragma unroll
            for (int Nt = 0; Nt < 8; ++Nt)
                out_pts[(long)g*128 + Nt*16 + l] = mm[Nt];
        }
    }

    #pragma unroll
    for (int t = 0; t < 8; ++t) {
        float a = s[t], b = sq[t];
        a += __shfl_xor(a, 16); a += __shfl_xor(a, 32);
        b += __shfl_xor(b, 16); b += __shfl_xor(b, 32);
        if (l < 16) { rbuf[wv][t*16 + l] = a; rbuf[wv][128 + t*16 + l] = b; }
    }
    __syncthreads();
    if (wv == 0 && l < 16) {
        #pragma unroll
        for (int t = 0; t < 8; ++t) {
            float a = rbuf[0][t*16+l] + rbuf[1][t*16+l] + rbuf[2][t*16+l] + rbuf[3][t*16+l];
            float b = rbuf[0][128+t*16+l] + rbuf[1][128+t*16+l] + rbuf[2][128+t*16+l] + rbuf[3][128+t*16+l];
            atomicAdd(&sums[256 + t*16 + l], a);
            atomicAdd(&sums[384 + t*16 + l], b);
        }
    }
}

// ================= fallback path (small ws): recompute, R4-style =================
template<int STAGE>
__global__ __launch_bounds__(256, 2) void k_passF(
    const float* __restrict__ xyz, const float* __restrict__ pts,
    const float* __restrict__ b0, const float* __restrict__ b1,
    const float* __restrict__ b2, const float* __restrict__ g2,
    float* __restrict__ ws, float* __restrict__ out_pts)
{
    __shared__ __align__(16) ushort zb[(STAGE >= 2) ? 4*32*136 : 8];
    const int tid = threadIdx.x;
    const int wv = tid >> 6, l = tid & 63, ln = l & 15, q8 = l >> 4;
    ushort* zw = &zb[(STAGE >= 2) ? wv*32*136 : 0];

    const ushort* idxw = (const ushort*)ws;
    const float* nxyz = ws + WS_NXYZ;
    const float* scl  = ws + WS_SCALE;
    float*       sums = ws + WS_SUMS;
    const uint4* w0f = (const uint4*)(ws + WS_W0PK);
    const uint4* w1f = (const uint4*)(ws + WS_W1PKD);
    const uint4* w2f = (const uint4*)(ws + WS_W2PKD);

    float b0v[4];
    #pragma unroll
    for (int n = 0; n < 4; ++n) b0v[n] = b0[n*16 + ln];
    float sc1v[4], sf1v[4], b1v[4];
    if constexpr (STAGE >= 2) {
        #pragma unroll
        for (int n = 0; n < 4; ++n) {
            sc1v[n] = scl[n*16 + ln]; sf1v[n] = scl[64 + n*16 + ln];
            b1v[n] = b1[n*16 + ln];
        }
    }
    float sc2v[4], sf2v[4], b2v[8], g2v[8];
    if constexpr (STAGE >= 3) {
        #pragma unroll
        for (int n = 0; n < 4; ++n) {
            sc2v[n] = scl[128 + n*16 + ln]; sf2v[n] = scl[192 + n*16 + ln];
        }
        #pragma unroll
        for (int n = 0; n < 8; ++n) { b2v[n] = b2[n*16 + ln]; g2v[n] = g2[n*16 + ln]; }
    }

    float s[8] = {0,0,0,0,0,0,0,0}, sq[8] = {0,0,0,0,0,0,0,0};

    for (int g = blockIdx.x*4 + wv; g < NG; g += 4096) {
        const float nqx = nxyz[g*3+0], nqy = nxyz[g*3+1], nqz = nxyz[g*3+2];
        short8 a1[2][3];
        #pragma unroll
        for (int Mt = 0; Mt < 2; ++Mt) {
            int nb = idxw[g*32 + Mt*16 + ln];
            int row = (g >> 10)*NN + nb;
            const float* p = pts + row*64 + q8*8;
            float4 f0 = *(const float4*)p, f1 = *(const float4*)(p + 4);
            float4 f2 = *(const float4*)(p + 32), f3 = *(const float4*)(p + 36);
            UF t0, t1;
            t0.u.x = pk2f(f0.x, f0.y); t0.u.y = pk2f(f0.z, f0.w);
            t0.u.z = pk2f(f1.x, f1.y); t0.u.w = pk2f(f1.z, f1.w);
            a1[Mt][0] = t0.s;
            t1.u.x = pk2f(f2.x, f2.y); t1.u.y = pk2f(f2.z, f2.w);
            t1.u.z = pk2f(f3.x, f3.y); t1.u.w = pk2f(f3.z, f3.w);
            a1[Mt][1] = t1.s;
            UF x; x.u = make_uint4(0,0,0,0);
            if (q8 == 0) {
                float vx = xyz[row*3+0] - nqx, vy = xyz[row*3+1] - nqy, vz = xyz[row*3+2] - nqz;
                unsigned bx = __float_as_uint(vx), by = __float_as_uint(vy), bz = __float_as_uint(vz);
                float rx = vx - __uint_as_float(bx & 0xffff0000u);
                float ry = vy - __uint_as_float(by & 0xffff0000u);
                float rz = vz - __uint_as_float(bz & 0xffff0000u);
                x.u.x = pk2r(bx, by);
                x.u.y = pk2r(bz, rtneb(rx));
                x.u.z = pk2r(rtneb(ry), rtneb(rz));
            }
            a1[Mt][2] = x.s;
        }

        float4v acc1[2][4];
        #pragma unroll
        for (int Mt = 0; Mt < 2; ++Mt)
            #pragma unroll
            for (int Nt = 0; Nt < 4; ++Nt)
                acc1[Mt][Nt] = (float4v){b0v[Nt], b0v[Nt], b0v[Nt], b0v[Nt]};
        #pragma unroll
        for (int Ks = 0; Ks < 3; ++Ks)
            #pragma unroll
            for (int Nt = 0; Nt < 4; ++Nt) {
                short8 bf = ldw(w0f, (Nt*3 + Ks)*64 + l);
                #pragma unroll
                for (int Mt = 0; Mt < 2; ++Mt)
                    acc1[Mt][Nt] = __builtin_amdgcn_mfma_f32_16x16x32_bf16(
                        a1[Mt][Ks], bf, acc1[Mt][Nt], 0, 0, 0);
            }

        if constexpr (STAGE == 1) {
            #pragma unroll
            for (int Nt = 0; Nt < 4; ++Nt)
                #pragma unroll
                for (int Mt = 0; Mt < 2; ++Mt)
                    #pragma unroll
                    for (int r = 0; r < 4; ++r) {
                        float h = acc1[Mt][Nt][r];
                        s[Nt] += h; sq[Nt] += h*h;
                    }
        }

        if constexpr (STAGE >= 2) {
            #pragma unroll
            for (int Mt = 0; Mt < 2; ++Mt)
                #pragma unroll
                for (int Nt = 0; Nt < 4; ++Nt)
                    #pragma unroll
                    for (int r = 0; r < 4; ++r) {
                        float z = fmaxf(fmaf(acc1[Mt][Nt][r], sc1v[Nt], sf1v[Nt]), 0.f);
                        unsigned zu = __float_as_uint(z);
                        float rr = z - __uint_as_float(zu & 0xffff0000u);
                        *(unsigned*)&zw[(Mt*16 + q8*4 + r)*136 + 2*(Nt*16 + ln)] = pk2r(zu, rtneb(rr));
                    }
            LDS_SYNC();

            float4v acc2[2][4];
            #pragma unroll
            for (int Mt = 0; Mt < 2; ++Mt)
                #pragma unroll
                for (int Nt = 0; Nt < 4; ++Nt)
                    acc2[Mt][Nt] = (float4v){b1v[Nt], b1v[Nt], b1v[Nt], b1v[Nt]};
            #pragma unroll
            for (int Ks = 0; Ks < 4; ++Ks) {
                short8 a2[2];
                #pragma unroll
                for (int Mt = 0; Mt < 2; ++Mt)
                    a2[Mt] = *(const short8*)&zw[(Mt*16 + ln)*136 + Ks*32 + q8*8];
                #pragma unroll
                for (int Nt = 0; Nt < 4; ++Nt) {
                    short8 bf = ldw(w1f, (Nt*4 + Ks)*64 + l);
                    #pragma unroll
                    for (int Mt = 0; Mt < 2; ++Mt)
                        acc2[Mt][Nt] = __builtin_amdgcn_mfma_f32_16x16x32_bf16(
                            a2[Mt], bf, acc2[Mt][Nt], 0, 0, 0);
                }
            }

            if constexpr (STAGE == 2) {
                #pragma unroll
                for (int Nt = 0; Nt < 4; ++Nt)
                    #pragma unroll
                    for (int Mt = 0; Mt < 2; ++Mt)
                        #pragma unroll
                        for (int r = 0; r < 4; ++r) {
                            float h = acc2[Mt][Nt][r];
                            s[Nt] += h; sq[Nt] += h*h;
                        }
            }

            if constexpr (STAGE == 3) {
                LDS_SYNC();
                #pragma unroll
                for (int Mt = 0; Mt < 2; ++Mt)
                    #pragma unroll
                    for (int Nt = 0; Nt < 4; ++Nt)
                        #pragma unroll
                        for (int r = 0; r < 4; ++r) {
                            float z = fmaxf(fmaf(acc2[Mt][Nt][r], sc2v[Nt], sf2v[Nt]), 0.f);
                            unsigned zu = __float_as_uint(z);
                            float rr = z - __uint_as_float(zu & 0xffff0000u);
                            *(unsigned*)&zw[(Mt*16 + q8*4 + r)*136 + 2*(Nt*16 + ln)] = pk2r(zu, rtneb(rr));
                        }
                LDS_SYNC();

                float4v acc3[2][8];
                #pragma unroll
                for (int Mt = 0; Mt < 2; ++Mt)
                    #pragma unroll
                    for (int Nt = 0; Nt < 8; ++Nt)
                        acc3[Mt][Nt] = (float4v){b2v[Nt], b2v[Nt], b2v[Nt], b2v[Nt]};
                #pragma unroll
                for (int Ks = 0; Ks < 4; ++Ks) {
                    short8 a2[2];
                    #pragma unroll
                    for (int Mt = 0; Mt < 2; ++Mt)
                        a2[Mt] = *(const short8*)&zw[(Mt*16 + ln)*136 + Ks*32 + q8*8];
                    #pragma unroll
                    for (int Nt = 0; Nt < 8; ++Nt) {
                        short8 bf = ldw(w2f, (Nt*4 + Ks)*64 + l);
                        #pragma unroll
                        for (int Mt = 0; Mt < 2; ++Mt)
                            acc3[Mt][Nt] = __builtin_amdgcn_mfma_f32_16x16x32_bf16(
                                a2[Mt], bf, acc3[Mt][Nt], 0, 0, 0);
                    }
                }

                float mm[8];
                #pragma unroll
                for (int Nt = 0; Nt < 8; ++Nt) {
                    const bool pos = g2v[Nt] >= 0.f;
                    float m = acc3[0][Nt][0];
                    #pragma unroll
                    for (int Mt = 0; Mt < 2; ++Mt)
                        #pragma unroll
                        for (int r = 0; r < 4; ++r) {
                            float h = acc3[Mt][Nt][r];
                            s[Nt] += h; sq[Nt] += h*h;
                            if (!(Mt == 0 && r == 0))
                                m = pos ? fmaxf(m, h) : fminf(m, h);
                        }
                    float o = __shfl_xor(m, 16); m = pos ? fmaxf(m, o) : fminf(m, o);
                    o = __shfl_xor(m, 32);       m = pos ? fmaxf(m, o) : fminf(m, o);
                    mm[Nt] = m;
                }
                if (l < 16) {
                    #pragma unroll
                    for (int Nt = 0; Nt < 8; ++Nt)
                        out_pts[(long)g*128 + Nt*16 + l] = mm[Nt];
                }
            }
        }
    }

    constexpr int NT = (STAGE == 3) ? 8 : 4;
    constexpr int soff = (STAGE == 1) ? 0 : (STAGE == 2) ? 128 : 256;
    constexpr int qoff = (STAGE == 1) ? 64 : (STAGE == 2) ? 192 : 384;
    #pragma unroll
    for (int t = 0; t < NT; ++t) {
        float a = s[t], b = sq[t];
        a += __shfl_xor(a, 16); a += __shfl_xor(a, 32);
        b += __shfl_xor(b, 16); b += __shfl_xor(b, 32);
        if (l < 16) {
            atomicAdd(&sums[soff + t*16 + l], a);
            atomicAdd(&sums[qoff + t*16 + l], b);
        }
    }
}

// ---------------- finalize: mean/var -> BN scale/shift ----------------
__global__ void k_fin(const float* __restrict__ sums, const float* __restrict__ g,
                      const float* __restrict__ be, float* __restrict__ scl,
                      int sum_off, int sq_off, int sc_off, int sh_off, int C)
{
    int c = threadIdx.x;
    if (c < C) {
        float mean = sums[sum_off + c] * (1.0f / PP);
        float var  = sums[sq_off + c] * (1.0f / PP) - mean * mean;
        float s = g[c] * rsqrtf(var + EPSF);
        scl[sc_off + c] = s;
        scl[sh_off + c] = be[c] - mean * s;
    }
}

// ---------------- apply BN3+ReLU to the pooled pre-activations ----------------
__global__ void k_bnmax(float* __restrict__ op, const float* __restrict__ scl) {
    int i = blockIdx.x * 256 + threadIdx.x;
    int c = i & 127;
    float sc = scl[256 + c], sf = scl[384 + c];
    op[i] = fmaxf(fmaf(op[i], sc, sf), 0.f);
}

extern "C" void kernel_launch(void* const* d_in, const int* in_sizes, int n_in,
                              void* d_out, int out_size, void* d_ws, size_t ws_size,
                              hipStream_t stream) {
    const float* xyz = (const float*)d_in[0];
    const float* pts = (const float*)d_in[1];
    const int*   fps = (const int*)d_in[2];
    const float* w0  = (const float*)d_in[3];
    const float* b0  = (const float*)d_in[4];
    const float* g0  = (const float*)d_in[5];
    const float* be0 = (const float*)d_in[6];
    const float* w1  = (const float*)d_in[7];
    const float* b1  = (const float*)d_in[8];
    const float* g1  = (const float*)d_in[9];
    const float* be1 = (const float*)d_in[10];
    const float* w2  = (const float*)d_in[11];
    const float* b2  = (const float*)d_in[12];
    const float* g2  = (const float*)d_in[13];
    const float* be2 = (const float*)d_in[14];

    float* ws = (float*)d_ws;
    float* out_xyz = (float*)d_out;
    float* out_pts = (float*)d_out + NG * 3;

    k_prep<<<1, 256, 0, stream>>>(w0, w1, w2, ws);
    k_select<<<NG / QPB, 512, 0, stream>>>(xyz, fps, out_xyz, ws);

    if (ws_size >= WS_FAST_BYTES) {
        ushort* h1 = (ushort*)(ws + WS_H1);
        ushort* h2 = (ushort*)(ws + WS_H2);
        k_g1<<<1024, 256, 0, stream>>>(xyz, pts, b0, ws, h1);
        k_fin<<<1, 128, 0, stream>>>(ws + WS_SUMS, g0, be0, ws + WS_SCALE, 0, 64, 0, 64, 64);
        k_g2<<<1024, 256, 0, stream>>>(b1, ws, h1, h2);
        k_fin<<<1, 128, 0, stream>>>(ws + WS_SUMS, g1, be1, ws + WS_SCALE, 128, 192, 128, 192, 64);
        k_g3<<<1024, 256, 0, stream>>>(b2, g2, ws, h2, out_pts);
        k_fin<<<1, 128, 0, stream>>>(ws + WS_SUMS, g2, be2, ws + WS_SCALE, 256, 384, 256, 384, 128);
    } else {
        k_passF<1><<<1024, 256, 0, stream>>>(xyz, pts, b0, b1, b2, g2, ws, out_pts);
        k_fin<<<1, 128, 0, stream>>>(ws + WS_SUMS, g0, be0, ws + WS_SCALE, 0, 64, 0, 64, 64);
        k_passF<2><<<1024, 256, 0, stream>>>(xyz, pts, b0, b1, b2, g2, ws, out_pts);
        k_fin<<<1, 128, 0, stream>>>(ws + WS_SUMS, g1, be1, ws + WS_SCALE, 128, 192, 128, 192, 64);
        k_passF<3><<<1024, 256, 0, stream>>>(xyz, pts, b0, b1, b2, g2, ws, out_pts);
        k_fin<<<1, 128, 0, stream>>>(ws + WS_SUMS, g2, be2, ws + WS_SCALE, 256, 384, 256, 384, 128);
    }
    k_bnmax<<<NG * 128 / 256, 256, 0, stream>>>(out_pts, ws + WS_SCALE);
}